// Round 8
// baseline (255.252 us; speedup 1.0000x reference)
//
#include <hip/hip_runtime.h>
#include <hip/hip_cooperative_groups.h>
#include <math.h>

#define BATCH 16384
#define B6 (BATCH*6)
#define DT 0.01f

using half8_t = __attribute__((ext_vector_type(8))) _Float16;
using half4_t = __attribute__((ext_vector_type(4))) _Float16;
using half2_t = __attribute__((ext_vector_type(2))) _Float16;
using f32x4   = __attribute__((ext_vector_type(4))) float;

__device__ __constant__ float c_LOWER[6]  = {-6.28f,-6.28f,-3.14f,-6.28f,-6.28f,-6.28f};
__device__ __constant__ float c_UPPER[6]  = { 6.28f, 6.28f, 3.14f, 6.28f, 6.28f, 6.28f};
__device__ __constant__ float c_EFFORT[6] = {150.0f,150.0f,150.0f,28.0f,28.0f,28.0f};
__device__ __constant__ int   c_ROWOFF[6] = {0,1,3,6,10,15};

__device__ __forceinline__ float sp_f(float z){
  return fmaxf(z,0.0f) + __logf(1.0f + __expf(-fabsf(z)));
}
__device__ __forceinline__ float sig_f(float z){
  return __builtin_amdgcn_rcpf(1.0f + __expf(-z));
}
// fused softplus+sigmoid sharing one exp (correctness-proven r6/r7)
__device__ __forceinline__ void spsig_f(float z, float& sp, float& sg){
  float e = __expf(-fabsf(z));
  float t = 1.0f + e;
  float r = __builtin_amdgcn_rcpf(t);
  sp = fmaxf(z,0.0f) + __logf(t);
  sg = (z >= 0.0f) ? r : e*r;
}

__device__ __forceinline__ float4 f4all(float v){ return make_float4(v,v,v,v); }
__device__ __forceinline__ void fma4(float4& acc, float w, float4 a){
  acc.x=fmaf(w,a.x,acc.x); acc.y=fmaf(w,a.y,acc.y); acc.z=fmaf(w,a.z,acc.z); acc.w=fmaf(w,a.w,acc.w);
}

// XOR-swizzled accessors for sh_t [12][16]
__device__ __forceinline__ const float4* chunkc(const float (*arr)[16], int n, int cc){
  return reinterpret_cast<const float4*>(&arr[n][4*(cc ^ ((n>>1)&3))]);
}
__device__ __forceinline__ float& el(float (*arr)[16], int n, int s){
  return arr[n][4*((s>>2) ^ ((n>>1)&3)) + (s&3)];
}

// ---- MFMA helpers --------------------------------------------------------
__device__ __forceinline__ f32x4 mfma3(half8_t ah, half8_t al, half8_t bh, half8_t bl, f32x4 acc){
  acc = __builtin_amdgcn_mfma_f32_16x16x32_f16(ah, bh, acc, 0,0,0);
  acc = __builtin_amdgcn_mfma_f32_16x16x32_f16(ah, bl, acc, 0,0,0);
  acc = __builtin_amdgcn_mfma_f32_16x16x32_f16(al, bh, acc, 0,0,0);
  return acc;
}
__device__ __forceinline__ f32x4 mfma1(half8_t ah, half8_t bh, f32x4 acc){
  return __builtin_amdgcn_mfma_f32_16x16x32_f16(ah, bh, acc, 0,0,0);
}
__device__ __forceinline__ half8_t ldB(const _Float16 (*B)[136], int n, int q, int quad){
  return *reinterpret_cast<const half8_t*>(&B[n][q*32 + quad*8]);
}
__device__ __forceinline__ void stB4(_Float16 (*Bh)[136], _Float16 (*Bl)[136], int n, int base, float4 v){
  half4_t hi, lo;
  const float* p = &v.x;
  #pragma unroll
  for (int j=0;j<4;j++){ hi[j] = (_Float16)p[j]; lo[j] = (_Float16)(p[j] - (float)hi[j]); }
  *reinterpret_cast<half4_t*>(&Bh[n][base]) = hi;
  *reinterpret_cast<half4_t*>(&Bl[n][base]) = lo;
}
__device__ __forceinline__ void stB2(_Float16 (*Bh)[136], _Float16 (*Bl)[136], int n, int k2, float a, float b){
  half2_t hi, lo;
  hi[0]=(_Float16)a; hi[1]=(_Float16)b;
  lo[0]=(_Float16)(a-(float)hi[0]); lo[1]=(_Float16)(b-(float)hi[1]);
  *reinterpret_cast<half2_t*>(&Bh[n][k2]) = hi;
  *reinterpret_cast<half2_t*>(&Bl[n][k2]) = lo;
}
// plain-fp16 stores (tangent path, r7-proven precision-safe)
__device__ __forceinline__ void stH2(_Float16 (*Bh)[136], int n, int k2, float a, float b){
  half2_t hi; hi[0]=(_Float16)a; hi[1]=(_Float16)b;
  *reinterpret_cast<half2_t*>(&Bh[n][k2]) = hi;
}
__device__ __forceinline__ void stH4(_Float16 (*Bh)[136], int n, int base, float4 v){
  half4_t hi;
  #pragma unroll
  for (int j=0;j<4;j++) hi[j] = (_Float16)(&v.x)[j];
  *reinterpret_cast<half4_t*>(&Bh[n][base]) = hi;
}

// ---------------- init + stage-0 pre body ----------------------------------
// viol[0] zeroed by hipMemsetAsync before (both paths); zeroes viol[1..3].
__device__ __forceinline__ void initpre_body(int t,
    const float* __restrict__ W1L, const float* __restrict__ W2L,
    const float* __restrict__ W3L, const float* __restrict__ W1V,
    const float* __restrict__ W2V, const float* __restrict__ b3L,
    const float* __restrict__ obs,
    float* __restrict__ W1LT, float* __restrict__ W1VT, float* __restrict__ b3Lp,
    _Float16* __restrict__ fragHi, _Float16* __restrict__ fragLo,
    float* __restrict__ q_cur, float* __restrict__ qd_cur, int* __restrict__ viol)
{
  if (t >= 1 && t < 4) viol[t] = 0;
  if (t < 1536){ int i = t/128, k = t%128; W1LT[t] = W1L[k*12+i]; W1VT[t] = W1V[k*12+i]; }
  if (t < 32) b3Lp[t] = (t < 21) ? b3L[t] : 0.0f;
  if (t < 6912){
    int kind, f;
    if (t < 2048){ kind=0; f=t; }
    else if (t < 4096){ kind=1; f=t-2048; }
    else if (t < 6144){ kind=2; f=t-4096; }
    else if (t < 6656){ kind=3; f=t-6144; }
    else { kind=4; f=t-6656; }
    int tile = f>>8, q = (f>>6)&3, l = f&63, m = l&15, kq = 8*(l>>4);
    int off = (kind==0?0:kind==1?16384:kind==2?32768:kind==3?49152:53248) + f*8;
    #pragma unroll
    for (int e=0;e<8;e++){
      float v;
      int kk = 32*q + kq + e;
      if (kind==0)      v = W2L[(16*tile+m)*128 + kk];
      else if (kind==1) v = W2V[(16*tile+m)*128 + kk];
      else if (kind==2) v = W2V[kk*128 + (16*tile+m)];
      else if (kind==3){ int r = 16*tile+m; v = (r<21) ? W3L[r*128 + kk] : 0.0f; }
      else              v = (m<12) ? W1V[kk*12 + m] : 0.0f;
      _Float16 hi = (_Float16)v;
      _Float16 lo = (_Float16)(v - (float)hi);
      fragHi[off+e] = hi; fragLo[off+e] = lo;
    }
  }
  if (t < BATCH){
    const float* o = obs + t*12;
    unsigned mask = 0;
    #pragma unroll
    for (int i=0;i<6;i++){
      float q = o[i];
      q_cur[t*6+i]=q; qd_cur[t*6+i]=o[6+i];
      float lo = c_LOWER[i]+0.1f, up = c_UPPER[i]-0.1f;
      if (q <= lo || q >= up) mask |= (1u<<i);
    }
    unsigned wm = 0;
    #pragma unroll
    for (int i=0;i<6;i++) if (__ballot((int)((mask>>i)&1u))) wm |= (1u<<i);
    if ((threadIdx.x & 63)==0 && wm) atomicOr(viol, (int)wm);
  }
}

// ---------------- heavy per-stage accel body (r7 content) ------------------
__device__ __forceinline__ void accel_body(
    int stage, bool fold_final,
    const float* __restrict__ obs,
    float* __restrict__ q_cur, float* __restrict__ qd_cur,
    const float* __restrict__ action,
    const float* __restrict__ W1LT, const float* __restrict__ b1L,
    const float* __restrict__ b2L,  const float* __restrict__ b3Lp,
    const float* __restrict__ W1VT, const float* __restrict__ b1V,
    const float* __restrict__ b2V,  const float* __restrict__ W3V,
    const float* __restrict__ W1V,
    const _Float16* __restrict__ fragHi, const _Float16* __restrict__ fragLo,
    int* __restrict__ viol,
    float* __restrict__ kqd_all,
    float* __restrict__ out)
{
  __shared__ alignas(16) _Float16 Bd[2][2][16][136];
  #define Bact Bd[0]
  __shared__ alignas(16) float sh_t[12][16];
  __shared__ float sh_y[21][17], sh_s3[21][17], sh_dy[42][17], sh_dv[12][17];
  __shared__ float sh_wg[2][6][16];
  __shared__ float sh_qd[6][16], sh_tau[6][16], sh_f[6][16];
  __shared__ float sh_c[6][16], sh_grav[6][16], sh_v[6][16];

  const int tid = threadIdx.x;
  const int l = tid & 63;
  const int w = tid >> 6;
  const int lane_n = l & 15;
  const int quad = l >> 4;
  const int base0 = w*16 + quad*4;
  const int base1 = (w+4)*16 + quad*4;
  const int s0 = blockIdx.x * 16;
  // agent-scope atomic load: not hoistable across grid.sync (fused path)
  const int vm = __hip_atomic_load(viol + stage, __ATOMIC_RELAXED, __HIP_MEMORY_SCOPE_AGENT);

  const half8_t* fW2Lh  = (const half8_t*)(fragHi);
  const half8_t* fW2Ll  = (const half8_t*)(fragLo);
  const half8_t* fW2Vh  = (const half8_t*)(fragHi + 16384);
  const half8_t* fW2Vl  = (const half8_t*)(fragLo + 16384);
  const half8_t* fW2VTh = (const half8_t*)(fragHi + 32768);
  const half8_t* fW2VTl = (const half8_t*)(fragLo + 32768);
  const half8_t* fW3h   = (const half8_t*)(fragHi + 49152);
  const half8_t* fW3l   = (const half8_t*)(fragLo + 49152);
  const half8_t* fW1Th  = (const half8_t*)(fragHi + 53248);
  const half8_t* fW1Tl  = (const half8_t*)(fragLo + 53248);

  // ---- phase 0: tile load, trig, tau, constraint force
  if (tid < 96){
    int s = tid & 15, i = tid >> 4;
    float q  = q_cur [(s0+s)*6 + i];
    float qd = qd_cur[(s0+s)*6 + i];
    sh_qd[i][s]=qd;
    sh_tau[i][s] = action[(s0+s)*6+i] * c_EFFORT[i];
    el(sh_t, 2*i,   s) = cosf(q);
    el(sh_t, 2*i+1, s) = sinf(q);
    float lo = c_LOWER[i]+0.1f, up = c_UPPER[i]-0.1f;
    float barrier = -5.0f*(1.0f/(q-lo) - 1.0f/(up-q));
    float clip = (q<=lo)? c_EFFORT[i] : ((q>=up)? -c_EFFORT[i] : 0.0f);
    sh_f[i][s] = ((vm>>i)&1) ? clip : barrier;
    sh_c[i][s] = 0.0f;
  }
  __syncthreads();

  float4 s1a, s1b;
  // ---- L1L (VALU) -> Bact
  {
    float2 bb = *reinterpret_cast<const float2*>(b1L + 2*l);
    float4 z0 = f4all(bb.x), z1 = f4all(bb.y);
    #pragma unroll
    for (int i=0;i<12;i++){
      float2 wv = *reinterpret_cast<const float2*>(W1LT + i*128 + 2*l);
      float4 a = *chunkc(sh_t, i, w);
      fma4(z0, wv.x, a); fma4(z1, wv.y, a);
    }
    float4 h0, h1;
    #pragma unroll
    for (int j=0;j<4;j++){
      spsig_f((&z0.x)[j], (&h0.x)[j], (&s1a.x)[j]);
      spsig_f((&z1.x)[j], (&h1.x)[j], (&s1b.x)[j]);
    }
    #pragma unroll
    for (int j=0;j<4;j++)
      stB2(Bact[0], Bact[1], 4*w+j, 2*l, (&h0.x)[j], (&h1.x)[j]);
  }
  __syncthreads();

  float4 s2a, s2b;
  // ---- L2L MFMA + epilogue (h2 -> Bact in-place)
  {
    f32x4 acc0 = {0.f,0.f,0.f,0.f}, acc1 = {0.f,0.f,0.f,0.f};
    #pragma unroll
    for (int q=0;q<4;q++){
      half8_t bh = ldB(Bact[0], lane_n, q, quad);
      half8_t bl = ldB(Bact[1], lane_n, q, quad);
      acc0 = mfma3(fW2Lh[(w*4+q)*64+l],     fW2Ll[(w*4+q)*64+l],     bh, bl, acc0);
      acc1 = mfma3(fW2Lh[((w+4)*4+q)*64+l], fW2Ll[((w+4)*4+q)*64+l], bh, bl, acc1);
    }
    __syncthreads();
    float4 ba = *reinterpret_cast<const float4*>(b2L + base0);
    float4 bb = *reinterpret_cast<const float4*>(b2L + base1);
    float4 h2a, h2b;
    #pragma unroll
    for (int j=0;j<4;j++){
      spsig_f(acc0[j] + (&ba.x)[j], (&h2a.x)[j], (&s2a.x)[j]);
      spsig_f(acc1[j] + (&bb.x)[j], (&h2b.x)[j], (&s2b.x)[j]);
    }
    stB4(Bact[0], Bact[1], lane_n, base0, h2a);
    stB4(Bact[0], Bact[1], lane_n, base1, h2b);
  }
  __syncthreads();

  // ---- L3 MFMA (waves 0,1) -> y, s3
  if (w < 2){
    f32x4 acc = {0.f,0.f,0.f,0.f};
    #pragma unroll
    for (int q=0;q<4;q++){
      half8_t bh = ldB(Bact[0], lane_n, q, quad);
      half8_t bl = ldB(Bact[1], lane_n, q, quad);
      acc = mfma3(fW3h[(w*4+q)*64+l], fW3l[(w*4+q)*64+l], bh, bl, acc);
    }
    int rb = w*16 + quad*4;
    #pragma unroll
    for (int j=0;j<4;j++){
      int r = rb + j;
      if (r < 21){
        float z = acc[j] + b3Lp[r];
        float sp, sg;
        spsig_f(z, sp, sg);
        sh_y[r][lane_n]  = sp;
        sh_s3[r][lane_n] = sg;
      }
    }
  }
  __syncthreads();
  // (Bact dead: sh_y/sh_s3 captured. Bd[0] free for tangents.)

  // ---- v = L^T qdot
  if (tid < 96){
    int s = tid & 15, jj = tid >> 4;
    float acc = 0.f;
    for (int i=jj;i<6;i++) acc = fmaf(sh_y[c_ROWOFF[i]+jj][s], sh_qd[i][s], acc);
    sh_v[jj][s] = acc;
  }

  // ---- tangent groups: dirs {2G, 2G+1} — plain fp16 path (r7)
  for (int G=0; G<3; ++G){
    #pragma unroll
    for (int d=0; d<2; ++d){
      int g = 2*G + d;
      float2 w0 = *reinterpret_cast<const float2*>(W1LT + (2*g)*128 + 2*l);
      float2 w1 = *reinterpret_cast<const float2*>(W1LT + (2*g+1)*128 + 2*l);
      float4 tc = *chunkc(sh_t, 2*g,   w);
      float4 ts = *chunkc(sh_t, 2*g+1, w);
      #pragma unroll
      for (int j=0;j<4;j++){
        float tcj = (&tc.x)[j], tsj = (&ts.x)[j];
        float d0 = (&s1a.x)[j]*(tcj*w1.x - tsj*w0.x);
        float d1 = (&s1b.x)[j]*(tcj*w1.y - tsj*w0.y);
        stH2(Bd[d][0], 4*w+j, 2*l, d0, d1);
      }
    }
    __syncthreads();
    f32x4 ta00={0.f,0.f,0.f,0.f}, ta01=ta00, ta10=ta00, ta11=ta00;
    #pragma unroll
    for (int q=0;q<4;q++){
      half8_t b0h = ldB(Bd[0][0], lane_n, q, quad);
      half8_t b1h = ldB(Bd[1][0], lane_n, q, quad);
      half8_t a0h = fW2Lh[(w*4+q)*64+l];
      half8_t a1h = fW2Lh[((w+4)*4+q)*64+l];
      ta00 = mfma1(a0h, b0h, ta00);
      ta01 = mfma1(a0h, b1h, ta01);
      ta10 = mfma1(a1h, b0h, ta10);
      ta11 = mfma1(a1h, b1h, ta11);
    }
    __syncthreads();
    {
      float4 v;
      #pragma unroll
      for (int j=0;j<4;j++) (&v.x)[j] = (&s2a.x)[j]*ta00[j];
      stH4(Bd[0][0], lane_n, base0, v);
      #pragma unroll
      for (int j=0;j<4;j++) (&v.x)[j] = (&s2b.x)[j]*ta10[j];
      stH4(Bd[0][0], lane_n, base1, v);
      #pragma unroll
      for (int j=0;j<4;j++) (&v.x)[j] = (&s2a.x)[j]*ta01[j];
      stH4(Bd[1][0], lane_n, base0, v);
      #pragma unroll
      for (int j=0;j<4;j++) (&v.x)[j] = (&s2b.x)[j]*ta11[j];
      stH4(Bd[1][0], lane_n, base1, v);
    }
    __syncthreads();
    {
      int d = w & 1, tt = w >> 1;
      f32x4 acc = {0.f,0.f,0.f,0.f};
      #pragma unroll
      for (int q=0;q<4;q++){
        half8_t bh = ldB(Bd[d][0], lane_n, q, quad);
        acc = mfma1(fW3h[(tt*4+q)*64+l], bh, acc);
      }
      int rb = tt*16 + quad*4;
      #pragma unroll
      for (int j=0;j<4;j++){
        int r = rb + j;
        if (r < 21) sh_dy[d*21 + r][lane_n] = sh_s3[r][lane_n] * acc[j];
      }
    }
    __syncthreads();
    if (tid < 32){
      int s = tid & 15, gg = tid >> 4;
      float qd[6];
      #pragma unroll
      for (int i=0;i<6;i++) qd[i] = sh_qd[i][s];
      float u[6];
      #pragma unroll
      for (int jj=0;jj<6;jj++){
        float acc = 0.f;
        for (int i=jj;i<6;i++) acc = fmaf(sh_dy[gg*21 + c_ROWOFF[i]+jj][s], qd[i], acc);
        u[jj] = acc;
      }
      #pragma unroll
      for (int i=0;i<6;i++){
        float acc = 0.f;
        for (int j=0;j<=i;j++){
          acc = fmaf(sh_dy[gg*21 + c_ROWOFF[i]+j][s], sh_v[j][s], acc);
          acc = fmaf(sh_y [c_ROWOFF[i]+j][s], u[j], acc);
        }
        sh_wg[gg][i][s] = acc;
      }
    }
    __syncthreads();
    if (tid < 96){
      int s = tid & 15, i = tid >> 4;
      float acc = sh_c[i][s];
      acc = fmaf(sh_qd[2*G][s],   sh_wg[0][i][s], acc);
      acc = fmaf(sh_qd[2*G+1][s], sh_wg[1][i][s], acc);
      int gi = i - 2*G;
      if (gi == 0 || gi == 1){
        float r = 0.f;
        #pragma unroll
        for (int j=0;j<6;j++) r = fmaf(sh_qd[j][s], sh_wg[gi][j][s], r);
        acc -= 0.5f*r;
      }
      sh_c[i][s] = acc;
    }
    __syncthreads();
  }

  // ---- V-net L1 (VALU) -> Bact
  {
    float2 bb = *reinterpret_cast<const float2*>(b1V + 2*l);
    float4 z0 = f4all(bb.x), z1 = f4all(bb.y);
    #pragma unroll
    for (int i=0;i<12;i++){
      float2 wv = *reinterpret_cast<const float2*>(W1VT + i*128 + 2*l);
      float4 a = *chunkc(sh_t, i, w);
      fma4(z0, wv.x, a); fma4(z1, wv.y, a);
    }
    #pragma unroll
    for (int j=0;j<4;j++){
      float h0 = sp_f((&z0.x)[j]);
      float h1 = sp_f((&z1.x)[j]);
      stB2(Bact[0], Bact[1], 4*w+j, 2*l, h0, h1);
    }
  }
  __syncthreads();
  // ---- L2V MFMA; epilogue g2 = sig(z)*W3V -> Bact in-place
  {
    f32x4 acc0 = {0.f,0.f,0.f,0.f}, acc1 = {0.f,0.f,0.f,0.f};
    #pragma unroll
    for (int q=0;q<4;q++){
      half8_t bh = ldB(Bact[0], lane_n, q, quad);
      half8_t bl = ldB(Bact[1], lane_n, q, quad);
      acc0 = mfma3(fW2Vh[(w*4+q)*64+l],     fW2Vl[(w*4+q)*64+l],     bh, bl, acc0);
      acc1 = mfma3(fW2Vh[((w+4)*4+q)*64+l], fW2Vl[((w+4)*4+q)*64+l], bh, bl, acc1);
    }
    __syncthreads();
    float4 ba  = *reinterpret_cast<const float4*>(b2V + base0);
    float4 bb  = *reinterpret_cast<const float4*>(b2V + base1);
    float4 w3a = *reinterpret_cast<const float4*>(W3V + base0);
    float4 w3b = *reinterpret_cast<const float4*>(W3V + base1);
    float4 g2a, g2b;
    #pragma unroll
    for (int j=0;j<4;j++){
      (&g2a.x)[j] = sig_f(acc0[j] + (&ba.x)[j]) * (&w3a.x)[j];
      (&g2b.x)[j] = sig_f(acc1[j] + (&bb.x)[j]) * (&w3b.x)[j];
    }
    stB4(Bact[0], Bact[1], lane_n, base0, g2a);
    stB4(Bact[0], Bact[1], lane_n, base1, g2b);
  }
  __syncthreads();
  // ---- V bwd MFMA (A = W2V^T); epilogue: recompute s1V, g1 -> Bd[0]
  {
    f32x4 acc0 = {0.f,0.f,0.f,0.f}, acc1 = {0.f,0.f,0.f,0.f};
    #pragma unroll
    for (int q=0;q<4;q++){
      half8_t bh = ldB(Bact[0], lane_n, q, quad);
      half8_t bl = ldB(Bact[1], lane_n, q, quad);
      acc0 = mfma3(fW2VTh[(w*4+q)*64+l],     fW2VTl[(w*4+q)*64+l],     bh, bl, acc0);
      acc1 = mfma3(fW2VTh[((w+4)*4+q)*64+l], fW2VTl[((w+4)*4+q)*64+l], bh, bl, acc1);
    }
    float tn[12];
    #pragma unroll
    for (int i=0;i<12;i++) tn[i] = el(sh_t, i, lane_n);
    float4 g1a, g1b;
    #pragma unroll
    for (int j=0;j<4;j++){
      int r = base0 + j;
      float z = b1V[r];
      const float* wr = W1V + r*12;
      #pragma unroll
      for (int i=0;i<12;i++) z = fmaf(wr[i], tn[i], z);
      (&g1a.x)[j] = sig_f(z) * acc0[j];
      r = base1 + j;
      z = b1V[r];
      wr = W1V + r*12;
      #pragma unroll
      for (int i=0;i<12;i++) z = fmaf(wr[i], tn[i], z);
      (&g1b.x)[j] = sig_f(z) * acc1[j];
    }
    __syncthreads();   // all g2 reads complete before g1 overwrite (alias)
    stB4(Bd[0][0], Bd[0][1], lane_n, base0, g1a);
    stB4(Bd[0][0], Bd[0][1], lane_n, base1, g1b);
  }
  __syncthreads();
  // ---- dV/dt = W1V^T g1 via MFMA (wave 0 only; A rows 12..15 zero)
  if (w == 0){
    f32x4 acc = {0.f,0.f,0.f,0.f};
    #pragma unroll
    for (int q=0;q<4;q++){
      half8_t bh = ldB(Bd[0][0], lane_n, q, quad);
      half8_t bl = ldB(Bd[0][1], lane_n, q, quad);
      acc = mfma3(fW1Th[q*64+l], fW1Tl[q*64+l], bh, bl, acc);
    }
    int rb = quad*4;
    #pragma unroll
    for (int j=0;j<4;j++){
      int r = rb + j;
      if (r < 12) sh_dv[r][lane_n] = acc[j];
    }
  }
  __syncthreads();
  // ---- gravity
  if (tid < 96){
    int k = tid>>4, s = tid&15;
    sh_grav[k][s] = fmaf(el(sh_t,2*k,s), sh_dv[2*k+1][s],
                         -(el(sh_t,2*k+1,s)*sh_dv[2*k][s]));
  }
  __syncthreads();
  // ---- assembly + triangular solves + folded next-stage pre (+ final)
  if (l < 4){
    int s = w*4 + l;
    float Lm[21];
    #pragma unroll
    for (int o=0;o<21;o++) Lm[o] = sh_y[o][s];
    float rhs[6];
    #pragma unroll
    for (int i=0;i<6;i++) rhs[i] = sh_tau[i][s] - sh_c[i][s] - sh_grav[i][s] - sh_f[i][s];
    float z[6];
    #pragma unroll
    for (int i=0;i<6;i++){
      float acc = rhs[i];
      for (int j=0;j<i;j++) acc = fmaf(-Lm[c_ROWOFF[i]+j], z[j], acc);
      z[i] = acc * __builtin_amdgcn_rcpf(Lm[c_ROWOFF[i]+i]);
    }
    float a[6];
    #pragma unroll
    for (int i=5;i>=0;i--){
      float acc = z[i];
      for (int j=i+1;j<6;j++) acc = fmaf(-Lm[c_ROWOFF[j]+i], a[j], acc);
      a[i] = acc * __builtin_amdgcn_rcpf(Lm[c_ROWOFF[i]+i]);
    }
    int b = s0 + s;
    float* kqd_out = kqd_all + stage*B6;
    #pragma unroll
    for (int i=0;i<6;i++) kqd_out[b*6+i] = a[i];

    if (stage < 3){
      const float* o = obs + b*12;
      unsigned mask = 0;
      #pragma unroll
      for (int i=0;i<6;i++){
        float q0=o[i], qd0=o[6+i];
        float q, qd;
        if (stage == 0){
          q  = q0 + 0.5f*DT*qd0;
          qd = qd0 + 0.5f*DT*a[i];
        } else if (stage == 1){
          float k1 = kqd_all[b*6+i];
          q  = q0 + 0.5f*DT*qd0 + 0.25f*DT*DT*k1;
          qd = qd0 + 0.5f*DT*a[i];
        } else {
          float k2 = kqd_all[B6 + b*6+i];
          q  = q0 + DT*qd0 + 0.5f*DT*DT*k2;
          qd = qd0 + DT*a[i];
        }
        q_cur[b*6+i]=q; qd_cur[b*6+i]=qd;
        float lo = c_LOWER[i]+0.1f, up = c_UPPER[i]-0.1f;
        if (q <= lo || q >= up) mask |= (1u<<i);
      }
      if (mask) atomicOr(viol + stage + 1, (int)mask);
    }

    if (fold_final){
      const float* o = obs + b*12;
      float* po = out + b*12;
      #pragma unroll
      for (int i=0;i<6;i++){
        float q0=o[i], qd0=o[6+i];
        float k1=kqd_all[b*6+i], k2=kqd_all[B6+b*6+i], k3=kqd_all[2*B6+b*6+i];
        float qn = q0 + DT*qd0 + (DT*DT/6.0f)*(k1+k2+k3);
        qn = fminf(fmaxf(qn, c_LOWER[i]), c_UPPER[i]);
        po[i] = qn;
        po[6+i] = qd0 + (DT/6.0f)*(k1 + 2.0f*k2 + 2.0f*k3 + a[i]);
      }
    }
  }
  #undef Bact
}

// ---------------- fallback kernels (measured-253µs 6-launch path) ----------
__global__ void __launch_bounds__(256) k_initpre(
    const float* __restrict__ W1L, const float* __restrict__ W2L,
    const float* __restrict__ W3L, const float* __restrict__ W1V,
    const float* __restrict__ W2V, const float* __restrict__ b3L,
    const float* __restrict__ obs,
    float* __restrict__ W1LT, float* __restrict__ W1VT, float* __restrict__ b3Lp,
    _Float16* __restrict__ fragHi, _Float16* __restrict__ fragLo,
    float* __restrict__ q_cur, float* __restrict__ qd_cur, int* __restrict__ viol)
{
  initpre_body(blockIdx.x*256 + threadIdx.x, W1L,W2L,W3L,W1V,W2V,b3L,obs,
               W1LT,W1VT,b3Lp,fragHi,fragLo,q_cur,qd_cur,viol);
}

__global__ void __launch_bounds__(256) k_accel(
    int stage, int fold_final,
    const float* __restrict__ obs,
    float* __restrict__ q_cur, float* __restrict__ qd_cur,
    const float* __restrict__ action,
    const float* __restrict__ W1LT, const float* __restrict__ b1L,
    const float* __restrict__ b2L,  const float* __restrict__ b3Lp,
    const float* __restrict__ W1VT, const float* __restrict__ b1V,
    const float* __restrict__ b2V,  const float* __restrict__ W3V,
    const float* __restrict__ W1V,
    const _Float16* __restrict__ fragHi, const _Float16* __restrict__ fragLo,
    int* __restrict__ viol,
    float* __restrict__ kqd_all,
    float* __restrict__ out)
{
  accel_body(stage, fold_final != 0, obs, q_cur, qd_cur, action, W1LT, b1L,
             b2L, b3Lp, W1VT, b1V, b2V, W3V, W1V, fragHi, fragLo, viol,
             kqd_all, out);
}

// ---------------- fused cooperative kernel ---------------------------------
// Re-attempt (r8): r7 body dropped VGPR 112->68, so the fused body should now
// certify 4 blocks/CU (needs VGPR<=128, LDS 28.2KB*4<=160KB). Plain
// __launch_bounds__(256) — NO min-waves clamp (r2: clamp => spill disaster).
// Host-side occupancy gate (r4-validated) prevents a failing launch inside
// graph capture; rejection falls back to the measured-253µs path.
__global__ void __launch_bounds__(256) k_fused(
    const float* __restrict__ obs, const float* __restrict__ action,
    const float* __restrict__ W1L, const float* __restrict__ b1L,
    const float* __restrict__ W2L, const float* __restrict__ b2L,
    const float* __restrict__ W3L, const float* __restrict__ b3L,
    const float* __restrict__ W1V, const float* __restrict__ b1V,
    const float* __restrict__ W2V, const float* __restrict__ b2V,
    const float* __restrict__ W3V,
    float* __restrict__ W1LT, float* __restrict__ W1VT, float* __restrict__ b3Lp,
    _Float16* __restrict__ fragHi, _Float16* __restrict__ fragLo,
    float* __restrict__ q_cur, float* __restrict__ qd_cur,
    float* __restrict__ kqd_all, int* __restrict__ viol, float* __restrict__ out)
{
  cooperative_groups::grid_group grid = cooperative_groups::this_grid();
  const int t = blockIdx.x*256 + threadIdx.x;

  // init + stage-0 pre (viol[0] pre-zeroed by stream memset)
  initpre_body(t, W1L,W2L,W3L,W1V,W2V,b3L,obs,
               W1LT,W1VT,b3Lp,fragHi,fragLo,q_cur,qd_cur,viol);
  __threadfence();
  grid.sync();

  // stages 0..3; grid sync between stages (viol[s+1] is batch-global OR,
  // q_cur/qd_cur are cross-block). unroll 1: single body copy for regalloc.
  #pragma unroll 1
  for (int stage = 0; stage < 4; ++stage){
    accel_body(stage, stage==3, obs, q_cur, qd_cur, action, W1LT, b1L, b2L,
               b3Lp, W1VT, b1V, b2V, W3V, W1V, fragHi, fragLo, viol, kqd_all, out);
    if (stage < 3){
      __threadfence();
      grid.sync();
    }
  }
}

extern "C" void kernel_launch(void* const* d_in, const int* in_sizes, int n_in,
                              void* d_out, int out_size, void* d_ws, size_t ws_size,
                              hipStream_t stream) {
  const float* obs    = (const float*)d_in[0];
  const float* action = (const float*)d_in[1];
  const float* W1L = (const float*)d_in[2];  const float* b1L = (const float*)d_in[3];
  const float* W2L = (const float*)d_in[4];  const float* b2L = (const float*)d_in[5];
  const float* W3L = (const float*)d_in[6];  const float* b3L = (const float*)d_in[7];
  const float* W1V = (const float*)d_in[8];  const float* b1V = (const float*)d_in[9];
  const float* W2V = (const float*)d_in[10]; const float* b2V = (const float*)d_in[11];
  const float* W3V = (const float*)d_in[12]; // b3V unused: only grad of V needed

  float* ws = (float*)d_ws;
  _Float16* fragHi = (_Float16*)ws;            // 55296 halves
  _Float16* fragLo = fragHi + 55296;           // 55296 halves
  float* W1LT  = ws + 55296;                   // 1536
  float* W1VT  = W1LT + 1536;                  // 1536
  float* b3Lp  = W1VT + 1536;                  // 32
  float* q_cur  = b3Lp + 32;                   // B6
  float* qd_cur = q_cur + B6;                  // B6
  float* kqd    = qd_cur + B6;                 // 4*B6
  int*   viol   = (int*)(kqd + 4*B6);

  float* out = (float*)d_out;

  // capture-safe path decision: pure driver queries, cached once (r4 lesson:
  // a FAILING coop launch inside graph capture poisons the capture).
  static int coop_ok = -1;
  if (coop_ok < 0){
    int nblk = 0, ncu = 0;
    hipError_t qe = hipOccupancyMaxActiveBlocksPerMultiprocessor(&nblk, (const void*)k_fused, 256, 0);
    hipError_t de = hipDeviceGetAttribute(&ncu, hipDeviceAttributeMultiprocessorCount, 0);
    coop_ok = (qe == hipSuccess && de == hipSuccess && (long)nblk * (long)ncu >= 1024) ? 1 : 0;
  }

  // viol[0] must be zero before the init kernel's atomicOr (both paths)
  hipMemsetAsync(viol, 0, sizeof(int), stream);

  bool launched = false;
  if (coop_ok == 1){
    void* kargs[] = {
      (void*)&obs, (void*)&action,
      (void*)&W1L, (void*)&b1L, (void*)&W2L, (void*)&b2L,
      (void*)&W3L, (void*)&b3L, (void*)&W1V, (void*)&b1V,
      (void*)&W2V, (void*)&b2V, (void*)&W3V,
      (void*)&W1LT, (void*)&W1VT, (void*)&b3Lp,
      (void*)&fragHi, (void*)&fragLo,
      (void*)&q_cur, (void*)&qd_cur, (void*)&kqd, (void*)&viol, (void*)&out
    };
    hipError_t e = hipLaunchCooperativeKernel((const void*)k_fused,
        dim3(1024), dim3(256), kargs, 0, stream);
    if (e == hipSuccess){
      launched = true;
    } else {
      (void)hipGetLastError();
      coop_ok = 0;
    }
  }

  if (!launched){
    k_initpre<<<64,256,0,stream>>>(W1L, W2L, W3L, W1V, W2V, b3L, obs,
                                   W1LT, W1VT, b3Lp, fragHi, fragLo,
                                   q_cur, qd_cur, viol);
    for (int s=0; s<4; ++s){
      k_accel<<<1024,256,0,stream>>>(s, (s==3)?1:0, obs, q_cur, qd_cur, action,
          W1LT, b1L, b2L, b3Lp, W1VT, b1V, b2V, W3V, W1V,
          fragHi, fragLo, viol, kqd, out);
    }
  }
}

// Round 9
// 253.658 us; speedup vs baseline: 1.0063x; 1.0063x over previous
//
#include <hip/hip_runtime.h>
#include <hip/hip_cooperative_groups.h>
#include <math.h>

#define BATCH 16384
#define B6 (BATCH*6)
#define DT 0.01f

using half8_t = __attribute__((ext_vector_type(8))) _Float16;
using half4_t = __attribute__((ext_vector_type(4))) _Float16;
using half2_t = __attribute__((ext_vector_type(2))) _Float16;
using f32x4   = __attribute__((ext_vector_type(4))) float;

__device__ __constant__ float c_LOWER[6]  = {-6.28f,-6.28f,-3.14f,-6.28f,-6.28f,-6.28f};
__device__ __constant__ float c_UPPER[6]  = { 6.28f, 6.28f, 3.14f, 6.28f, 6.28f, 6.28f};
__device__ __constant__ float c_EFFORT[6] = {150.0f,150.0f,150.0f,28.0f,28.0f,28.0f};
__device__ __constant__ int   c_ROWOFF[6] = {0,1,3,6,10,15};

__device__ __forceinline__ float sp_f(float z){
  return fmaxf(z,0.0f) + __logf(1.0f + __expf(-fabsf(z)));
}
__device__ __forceinline__ float sig_f(float z){
  return __builtin_amdgcn_rcpf(1.0f + __expf(-z));
}
// fused softplus+sigmoid sharing one exp (correctness-proven r6/r7)
__device__ __forceinline__ void spsig_f(float z, float& sp, float& sg){
  float e = __expf(-fabsf(z));
  float t = 1.0f + e;
  float r = __builtin_amdgcn_rcpf(t);
  sp = fmaxf(z,0.0f) + __logf(t);
  sg = (z >= 0.0f) ? r : e*r;
}

__device__ __forceinline__ float4 f4all(float v){ return make_float4(v,v,v,v); }
__device__ __forceinline__ void fma4(float4& acc, float w, float4 a){
  acc.x=fmaf(w,a.x,acc.x); acc.y=fmaf(w,a.y,acc.y); acc.z=fmaf(w,a.z,acc.z); acc.w=fmaf(w,a.w,acc.w);
}

// XOR-swizzled accessors for sh_t [12][16]
__device__ __forceinline__ const float4* chunkc(const float (*arr)[16], int n, int cc){
  return reinterpret_cast<const float4*>(&arr[n][4*(cc ^ ((n>>1)&3))]);
}
__device__ __forceinline__ float& el(float (*arr)[16], int n, int s){
  return arr[n][4*((s>>2) ^ ((n>>1)&3)) + (s&3)];
}

// ---- MFMA helpers --------------------------------------------------------
__device__ __forceinline__ f32x4 mfma3(half8_t ah, half8_t al, half8_t bh, half8_t bl, f32x4 acc){
  acc = __builtin_amdgcn_mfma_f32_16x16x32_f16(ah, bh, acc, 0,0,0);
  acc = __builtin_amdgcn_mfma_f32_16x16x32_f16(ah, bl, acc, 0,0,0);
  acc = __builtin_amdgcn_mfma_f32_16x16x32_f16(al, bh, acc, 0,0,0);
  return acc;
}
__device__ __forceinline__ f32x4 mfma1(half8_t ah, half8_t bh, f32x4 acc){
  return __builtin_amdgcn_mfma_f32_16x16x32_f16(ah, bh, acc, 0,0,0);
}
__device__ __forceinline__ half8_t ldB(const _Float16 (*B)[136], int n, int q, int quad){
  return *reinterpret_cast<const half8_t*>(&B[n][q*32 + quad*8]);
}
__device__ __forceinline__ void stB4(_Float16 (*Bh)[136], _Float16 (*Bl)[136], int n, int base, float4 v){
  half4_t hi, lo;
  const float* p = &v.x;
  #pragma unroll
  for (int j=0;j<4;j++){ hi[j] = (_Float16)p[j]; lo[j] = (_Float16)(p[j] - (float)hi[j]); }
  *reinterpret_cast<half4_t*>(&Bh[n][base]) = hi;
  *reinterpret_cast<half4_t*>(&Bl[n][base]) = lo;
}
__device__ __forceinline__ void stB2(_Float16 (*Bh)[136], _Float16 (*Bl)[136], int n, int k2, float a, float b){
  half2_t hi, lo;
  hi[0]=(_Float16)a; hi[1]=(_Float16)b;
  lo[0]=(_Float16)(a-(float)hi[0]); lo[1]=(_Float16)(b-(float)hi[1]);
  *reinterpret_cast<half2_t*>(&Bh[n][k2]) = hi;
  *reinterpret_cast<half2_t*>(&Bl[n][k2]) = lo;
}
// plain-fp16 stores (tangent path, r7-proven precision-safe)
__device__ __forceinline__ void stH2(_Float16 (*Bh)[136], int n, int k2, float a, float b){
  half2_t hi; hi[0]=(_Float16)a; hi[1]=(_Float16)b;
  *reinterpret_cast<half2_t*>(&Bh[n][k2]) = hi;
}
__device__ __forceinline__ void stH4(_Float16 (*Bh)[136], int n, int base, float4 v){
  half4_t hi;
  #pragma unroll
  for (int j=0;j<4;j++) hi[j] = (_Float16)(&v.x)[j];
  *reinterpret_cast<half4_t*>(&Bh[n][base]) = hi;
}

// ---------------- init + stage-0 pre (ALWAYS its own kernel) ---------------
// r9: kept OUT of the fused kernel — its 8-wide conversion loop + 5-way
// branching inflates whole-kernel regalloc; both r4 and r8 coop rejections
// are consistent with initpre pushing fused VGPR past the 128 needed for
// 4 blocks/CU. viol[0] zeroed by hipMemsetAsync before this kernel.
__global__ void __launch_bounds__(256) k_initpre(
    const float* __restrict__ W1L, const float* __restrict__ W2L,
    const float* __restrict__ W3L, const float* __restrict__ W1V,
    const float* __restrict__ W2V, const float* __restrict__ b3L,
    const float* __restrict__ obs,
    float* __restrict__ W1LT, float* __restrict__ W1VT, float* __restrict__ b3Lp,
    _Float16* __restrict__ fragHi, _Float16* __restrict__ fragLo,
    float* __restrict__ q_cur, float* __restrict__ qd_cur, int* __restrict__ viol)
{
  int t = blockIdx.x*256 + threadIdx.x;
  if (t >= 1 && t < 4) viol[t] = 0;
  if (t < 1536){ int i = t/128, k = t%128; W1LT[t] = W1L[k*12+i]; W1VT[t] = W1V[k*12+i]; }
  if (t < 32) b3Lp[t] = (t < 21) ? b3L[t] : 0.0f;
  if (t < 6912){
    int kind, f;
    if (t < 2048){ kind=0; f=t; }
    else if (t < 4096){ kind=1; f=t-2048; }
    else if (t < 6144){ kind=2; f=t-4096; }
    else if (t < 6656){ kind=3; f=t-6144; }
    else { kind=4; f=t-6656; }
    int tile = f>>8, q = (f>>6)&3, l = f&63, m = l&15, kq = 8*(l>>4);
    int off = (kind==0?0:kind==1?16384:kind==2?32768:kind==3?49152:53248) + f*8;
    #pragma unroll
    for (int e=0;e<8;e++){
      float v;
      int kk = 32*q + kq + e;
      if (kind==0)      v = W2L[(16*tile+m)*128 + kk];
      else if (kind==1) v = W2V[(16*tile+m)*128 + kk];
      else if (kind==2) v = W2V[kk*128 + (16*tile+m)];
      else if (kind==3){ int r = 16*tile+m; v = (r<21) ? W3L[r*128 + kk] : 0.0f; }
      else              v = (m<12) ? W1V[kk*12 + m] : 0.0f;
      _Float16 hi = (_Float16)v;
      _Float16 lo = (_Float16)(v - (float)hi);
      fragHi[off+e] = hi; fragLo[off+e] = lo;
    }
  }
  if (t < BATCH){
    const float* o = obs + t*12;
    unsigned mask = 0;
    #pragma unroll
    for (int i=0;i<6;i++){
      float q = o[i];
      q_cur[t*6+i]=q; qd_cur[t*6+i]=o[6+i];
      float lo = c_LOWER[i]+0.1f, up = c_UPPER[i]-0.1f;
      if (q <= lo || q >= up) mask |= (1u<<i);
    }
    unsigned wm = 0;
    #pragma unroll
    for (int i=0;i<6;i++) if (__ballot((int)((mask>>i)&1u))) wm |= (1u<<i);
    if ((threadIdx.x & 63)==0 && wm) atomicOr(viol, (int)wm);
  }
}

// ---------------- heavy per-stage accel body (r7 content) ------------------
__device__ __forceinline__ void accel_body(
    int stage, bool fold_final,
    const float* __restrict__ obs,
    float* __restrict__ q_cur, float* __restrict__ qd_cur,
    const float* __restrict__ action,
    const float* __restrict__ W1LT, const float* __restrict__ b1L,
    const float* __restrict__ b2L,  const float* __restrict__ b3Lp,
    const float* __restrict__ W1VT, const float* __restrict__ b1V,
    const float* __restrict__ b2V,  const float* __restrict__ W3V,
    const float* __restrict__ W1V,
    const _Float16* __restrict__ fragHi, const _Float16* __restrict__ fragLo,
    int* __restrict__ viol,
    float* __restrict__ kqd_all,
    float* __restrict__ out)
{
  __shared__ alignas(16) _Float16 Bd[2][2][16][136];
  #define Bact Bd[0]
  __shared__ alignas(16) float sh_t[12][16];
  __shared__ float sh_y[21][17], sh_s3[21][17], sh_dy[42][17], sh_dv[12][17];
  __shared__ float sh_wg[2][6][16];
  __shared__ float sh_qd[6][16], sh_tau[6][16], sh_f[6][16];
  __shared__ float sh_c[6][16], sh_grav[6][16], sh_v[6][16];

  const int tid = threadIdx.x;
  const int l = tid & 63;
  const int w = tid >> 6;
  const int lane_n = l & 15;
  const int quad = l >> 4;
  const int base0 = w*16 + quad*4;
  const int base1 = (w+4)*16 + quad*4;
  const int s0 = blockIdx.x * 16;
  // agent-scope atomic load: not hoistable across grid.sync (fused path)
  const int vm = __hip_atomic_load(viol + stage, __ATOMIC_RELAXED, __HIP_MEMORY_SCOPE_AGENT);

  const half8_t* fW2Lh  = (const half8_t*)(fragHi);
  const half8_t* fW2Ll  = (const half8_t*)(fragLo);
  const half8_t* fW2Vh  = (const half8_t*)(fragHi + 16384);
  const half8_t* fW2Vl  = (const half8_t*)(fragLo + 16384);
  const half8_t* fW2VTh = (const half8_t*)(fragHi + 32768);
  const half8_t* fW2VTl = (const half8_t*)(fragLo + 32768);
  const half8_t* fW3h   = (const half8_t*)(fragHi + 49152);
  const half8_t* fW3l   = (const half8_t*)(fragLo + 49152);
  const half8_t* fW1Th  = (const half8_t*)(fragHi + 53248);
  const half8_t* fW1Tl  = (const half8_t*)(fragLo + 53248);

  // ---- phase 0: tile load, trig, tau, constraint force
  if (tid < 96){
    int s = tid & 15, i = tid >> 4;
    float q  = q_cur [(s0+s)*6 + i];
    float qd = qd_cur[(s0+s)*6 + i];
    sh_qd[i][s]=qd;
    sh_tau[i][s] = action[(s0+s)*6+i] * c_EFFORT[i];
    el(sh_t, 2*i,   s) = cosf(q);
    el(sh_t, 2*i+1, s) = sinf(q);
    float lo = c_LOWER[i]+0.1f, up = c_UPPER[i]-0.1f;
    float barrier = -5.0f*(1.0f/(q-lo) - 1.0f/(up-q));
    float clip = (q<=lo)? c_EFFORT[i] : ((q>=up)? -c_EFFORT[i] : 0.0f);
    sh_f[i][s] = ((vm>>i)&1) ? clip : barrier;
    sh_c[i][s] = 0.0f;
  }
  __syncthreads();

  float4 s1a, s1b;
  // ---- L1L (VALU) -> Bact
  {
    float2 bb = *reinterpret_cast<const float2*>(b1L + 2*l);
    float4 z0 = f4all(bb.x), z1 = f4all(bb.y);
    #pragma unroll
    for (int i=0;i<12;i++){
      float2 wv = *reinterpret_cast<const float2*>(W1LT + i*128 + 2*l);
      float4 a = *chunkc(sh_t, i, w);
      fma4(z0, wv.x, a); fma4(z1, wv.y, a);
    }
    float4 h0, h1;
    #pragma unroll
    for (int j=0;j<4;j++){
      spsig_f((&z0.x)[j], (&h0.x)[j], (&s1a.x)[j]);
      spsig_f((&z1.x)[j], (&h1.x)[j], (&s1b.x)[j]);
    }
    #pragma unroll
    for (int j=0;j<4;j++)
      stB2(Bact[0], Bact[1], 4*w+j, 2*l, (&h0.x)[j], (&h1.x)[j]);
  }
  __syncthreads();

  float4 s2a, s2b;
  // ---- L2L MFMA + epilogue (h2 -> Bact in-place)
  {
    f32x4 acc0 = {0.f,0.f,0.f,0.f}, acc1 = {0.f,0.f,0.f,0.f};
    #pragma unroll
    for (int q=0;q<4;q++){
      half8_t bh = ldB(Bact[0], lane_n, q, quad);
      half8_t bl = ldB(Bact[1], lane_n, q, quad);
      acc0 = mfma3(fW2Lh[(w*4+q)*64+l],     fW2Ll[(w*4+q)*64+l],     bh, bl, acc0);
      acc1 = mfma3(fW2Lh[((w+4)*4+q)*64+l], fW2Ll[((w+4)*4+q)*64+l], bh, bl, acc1);
    }
    __syncthreads();
    float4 ba = *reinterpret_cast<const float4*>(b2L + base0);
    float4 bb = *reinterpret_cast<const float4*>(b2L + base1);
    float4 h2a, h2b;
    #pragma unroll
    for (int j=0;j<4;j++){
      spsig_f(acc0[j] + (&ba.x)[j], (&h2a.x)[j], (&s2a.x)[j]);
      spsig_f(acc1[j] + (&bb.x)[j], (&h2b.x)[j], (&s2b.x)[j]);
    }
    stB4(Bact[0], Bact[1], lane_n, base0, h2a);
    stB4(Bact[0], Bact[1], lane_n, base1, h2b);
  }
  __syncthreads();

  // ---- L3 MFMA (waves 0,1) -> y, s3
  if (w < 2){
    f32x4 acc = {0.f,0.f,0.f,0.f};
    #pragma unroll
    for (int q=0;q<4;q++){
      half8_t bh = ldB(Bact[0], lane_n, q, quad);
      half8_t bl = ldB(Bact[1], lane_n, q, quad);
      acc = mfma3(fW3h[(w*4+q)*64+l], fW3l[(w*4+q)*64+l], bh, bl, acc);
    }
    int rb = w*16 + quad*4;
    #pragma unroll
    for (int j=0;j<4;j++){
      int r = rb + j;
      if (r < 21){
        float z = acc[j] + b3Lp[r];
        float sp, sg;
        spsig_f(z, sp, sg);
        sh_y[r][lane_n]  = sp;
        sh_s3[r][lane_n] = sg;
      }
    }
  }
  __syncthreads();
  // (Bact dead: sh_y/sh_s3 captured. Bd[0] free for tangents.)

  // ---- v = L^T qdot
  if (tid < 96){
    int s = tid & 15, jj = tid >> 4;
    float acc = 0.f;
    for (int i=jj;i<6;i++) acc = fmaf(sh_y[c_ROWOFF[i]+jj][s], sh_qd[i][s], acc);
    sh_v[jj][s] = acc;
  }

  // ---- tangent groups: dirs {2G, 2G+1} — plain fp16 path (r7)
  for (int G=0; G<3; ++G){
    #pragma unroll
    for (int d=0; d<2; ++d){
      int g = 2*G + d;
      float2 w0 = *reinterpret_cast<const float2*>(W1LT + (2*g)*128 + 2*l);
      float2 w1 = *reinterpret_cast<const float2*>(W1LT + (2*g+1)*128 + 2*l);
      float4 tc = *chunkc(sh_t, 2*g,   w);
      float4 ts = *chunkc(sh_t, 2*g+1, w);
      #pragma unroll
      for (int j=0;j<4;j++){
        float tcj = (&tc.x)[j], tsj = (&ts.x)[j];
        float d0 = (&s1a.x)[j]*(tcj*w1.x - tsj*w0.x);
        float d1 = (&s1b.x)[j]*(tcj*w1.y - tsj*w0.y);
        stH2(Bd[d][0], 4*w+j, 2*l, d0, d1);
      }
    }
    __syncthreads();
    f32x4 ta00={0.f,0.f,0.f,0.f}, ta01=ta00, ta10=ta00, ta11=ta00;
    #pragma unroll
    for (int q=0;q<4;q++){
      half8_t b0h = ldB(Bd[0][0], lane_n, q, quad);
      half8_t b1h = ldB(Bd[1][0], lane_n, q, quad);
      half8_t a0h = fW2Lh[(w*4+q)*64+l];
      half8_t a1h = fW2Lh[((w+4)*4+q)*64+l];
      ta00 = mfma1(a0h, b0h, ta00);
      ta01 = mfma1(a0h, b1h, ta01);
      ta10 = mfma1(a1h, b0h, ta10);
      ta11 = mfma1(a1h, b1h, ta11);
    }
    __syncthreads();
    {
      float4 v;
      #pragma unroll
      for (int j=0;j<4;j++) (&v.x)[j] = (&s2a.x)[j]*ta00[j];
      stH4(Bd[0][0], lane_n, base0, v);
      #pragma unroll
      for (int j=0;j<4;j++) (&v.x)[j] = (&s2b.x)[j]*ta10[j];
      stH4(Bd[0][0], lane_n, base1, v);
      #pragma unroll
      for (int j=0;j<4;j++) (&v.x)[j] = (&s2a.x)[j]*ta01[j];
      stH4(Bd[1][0], lane_n, base0, v);
      #pragma unroll
      for (int j=0;j<4;j++) (&v.x)[j] = (&s2b.x)[j]*ta11[j];
      stH4(Bd[1][0], lane_n, base1, v);
    }
    __syncthreads();
    {
      int d = w & 1, tt = w >> 1;
      f32x4 acc = {0.f,0.f,0.f,0.f};
      #pragma unroll
      for (int q=0;q<4;q++){
        half8_t bh = ldB(Bd[d][0], lane_n, q, quad);
        acc = mfma1(fW3h[(tt*4+q)*64+l], bh, acc);
      }
      int rb = tt*16 + quad*4;
      #pragma unroll
      for (int j=0;j<4;j++){
        int r = rb + j;
        if (r < 21) sh_dy[d*21 + r][lane_n] = sh_s3[r][lane_n] * acc[j];
      }
    }
    __syncthreads();
    if (tid < 32){
      int s = tid & 15, gg = tid >> 4;
      float qd[6];
      #pragma unroll
      for (int i=0;i<6;i++) qd[i] = sh_qd[i][s];
      float u[6];
      #pragma unroll
      for (int jj=0;jj<6;jj++){
        float acc = 0.f;
        for (int i=jj;i<6;i++) acc = fmaf(sh_dy[gg*21 + c_ROWOFF[i]+jj][s], qd[i], acc);
        u[jj] = acc;
      }
      #pragma unroll
      for (int i=0;i<6;i++){
        float acc = 0.f;
        for (int j=0;j<=i;j++){
          acc = fmaf(sh_dy[gg*21 + c_ROWOFF[i]+j][s], sh_v[j][s], acc);
          acc = fmaf(sh_y [c_ROWOFF[i]+j][s], u[j], acc);
        }
        sh_wg[gg][i][s] = acc;
      }
    }
    __syncthreads();
    if (tid < 96){
      int s = tid & 15, i = tid >> 4;
      float acc = sh_c[i][s];
      acc = fmaf(sh_qd[2*G][s],   sh_wg[0][i][s], acc);
      acc = fmaf(sh_qd[2*G+1][s], sh_wg[1][i][s], acc);
      int gi = i - 2*G;
      if (gi == 0 || gi == 1){
        float r = 0.f;
        #pragma unroll
        for (int j=0;j<6;j++) r = fmaf(sh_qd[j][s], sh_wg[gi][j][s], r);
        acc -= 0.5f*r;
      }
      sh_c[i][s] = acc;
    }
    __syncthreads();
  }

  // ---- V-net L1 (VALU) -> Bact
  {
    float2 bb = *reinterpret_cast<const float2*>(b1V + 2*l);
    float4 z0 = f4all(bb.x), z1 = f4all(bb.y);
    #pragma unroll
    for (int i=0;i<12;i++){
      float2 wv = *reinterpret_cast<const float2*>(W1VT + i*128 + 2*l);
      float4 a = *chunkc(sh_t, i, w);
      fma4(z0, wv.x, a); fma4(z1, wv.y, a);
    }
    #pragma unroll
    for (int j=0;j<4;j++){
      float h0 = sp_f((&z0.x)[j]);
      float h1 = sp_f((&z1.x)[j]);
      stB2(Bact[0], Bact[1], 4*w+j, 2*l, h0, h1);
    }
  }
  __syncthreads();
  // ---- L2V MFMA; epilogue g2 = sig(z)*W3V -> Bact in-place
  {
    f32x4 acc0 = {0.f,0.f,0.f,0.f}, acc1 = {0.f,0.f,0.f,0.f};
    #pragma unroll
    for (int q=0;q<4;q++){
      half8_t bh = ldB(Bact[0], lane_n, q, quad);
      half8_t bl = ldB(Bact[1], lane_n, q, quad);
      acc0 = mfma3(fW2Vh[(w*4+q)*64+l],     fW2Vl[(w*4+q)*64+l],     bh, bl, acc0);
      acc1 = mfma3(fW2Vh[((w+4)*4+q)*64+l], fW2Vl[((w+4)*4+q)*64+l], bh, bl, acc1);
    }
    __syncthreads();
    float4 ba  = *reinterpret_cast<const float4*>(b2V + base0);
    float4 bb  = *reinterpret_cast<const float4*>(b2V + base1);
    float4 w3a = *reinterpret_cast<const float4*>(W3V + base0);
    float4 w3b = *reinterpret_cast<const float4*>(W3V + base1);
    float4 g2a, g2b;
    #pragma unroll
    for (int j=0;j<4;j++){
      (&g2a.x)[j] = sig_f(acc0[j] + (&ba.x)[j]) * (&w3a.x)[j];
      (&g2b.x)[j] = sig_f(acc1[j] + (&bb.x)[j]) * (&w3b.x)[j];
    }
    stB4(Bact[0], Bact[1], lane_n, base0, g2a);
    stB4(Bact[0], Bact[1], lane_n, base1, g2b);
  }
  __syncthreads();
  // ---- V bwd MFMA (A = W2V^T); epilogue: recompute s1V, g1 -> Bd[0]
  {
    f32x4 acc0 = {0.f,0.f,0.f,0.f}, acc1 = {0.f,0.f,0.f,0.f};
    #pragma unroll
    for (int q=0;q<4;q++){
      half8_t bh = ldB(Bact[0], lane_n, q, quad);
      half8_t bl = ldB(Bact[1], lane_n, q, quad);
      acc0 = mfma3(fW2VTh[(w*4+q)*64+l],     fW2VTl[(w*4+q)*64+l],     bh, bl, acc0);
      acc1 = mfma3(fW2VTh[((w+4)*4+q)*64+l], fW2VTl[((w+4)*4+q)*64+l], bh, bl, acc1);
    }
    float tn[12];
    #pragma unroll
    for (int i=0;i<12;i++) tn[i] = el(sh_t, i, lane_n);
    float4 g1a, g1b;
    #pragma unroll
    for (int j=0;j<4;j++){
      int r = base0 + j;
      float z = b1V[r];
      const float* wr = W1V + r*12;
      #pragma unroll
      for (int i=0;i<12;i++) z = fmaf(wr[i], tn[i], z);
      (&g1a.x)[j] = sig_f(z) * acc0[j];
      r = base1 + j;
      z = b1V[r];
      wr = W1V + r*12;
      #pragma unroll
      for (int i=0;i<12;i++) z = fmaf(wr[i], tn[i], z);
      (&g1b.x)[j] = sig_f(z) * acc1[j];
    }
    __syncthreads();   // all g2 reads complete before g1 overwrite (alias)
    stB4(Bd[0][0], Bd[0][1], lane_n, base0, g1a);
    stB4(Bd[0][0], Bd[0][1], lane_n, base1, g1b);
  }
  __syncthreads();
  // ---- dV/dt = W1V^T g1 via MFMA (wave 0 only; A rows 12..15 zero)
  if (w == 0){
    f32x4 acc = {0.f,0.f,0.f,0.f};
    #pragma unroll
    for (int q=0;q<4;q++){
      half8_t bh = ldB(Bd[0][0], lane_n, q, quad);
      half8_t bl = ldB(Bd[0][1], lane_n, q, quad);
      acc = mfma3(fW1Th[q*64+l], fW1Tl[q*64+l], bh, bl, acc);
    }
    int rb = quad*4;
    #pragma unroll
    for (int j=0;j<4;j++){
      int r = rb + j;
      if (r < 12) sh_dv[r][lane_n] = acc[j];
    }
  }
  __syncthreads();
  // ---- gravity
  if (tid < 96){
    int k = tid>>4, s = tid&15;
    sh_grav[k][s] = fmaf(el(sh_t,2*k,s), sh_dv[2*k+1][s],
                         -(el(sh_t,2*k+1,s)*sh_dv[2*k][s]));
  }
  __syncthreads();
  // ---- assembly + triangular solves + folded next-stage pre (+ final)
  if (l < 4){
    int s = w*4 + l;
    float Lm[21];
    #pragma unroll
    for (int o=0;o<21;o++) Lm[o] = sh_y[o][s];
    float rhs[6];
    #pragma unroll
    for (int i=0;i<6;i++) rhs[i] = sh_tau[i][s] - sh_c[i][s] - sh_grav[i][s] - sh_f[i][s];
    float z[6];
    #pragma unroll
    for (int i=0;i<6;i++){
      float acc = rhs[i];
      for (int j=0;j<i;j++) acc = fmaf(-Lm[c_ROWOFF[i]+j], z[j], acc);
      z[i] = acc * __builtin_amdgcn_rcpf(Lm[c_ROWOFF[i]+i]);
    }
    float a[6];
    #pragma unroll
    for (int i=5;i>=0;i--){
      float acc = z[i];
      for (int j=i+1;j<6;j++) acc = fmaf(-Lm[c_ROWOFF[j]+i], a[j], acc);
      a[i] = acc * __builtin_amdgcn_rcpf(Lm[c_ROWOFF[i]+i]);
    }
    int b = s0 + s;
    float* kqd_out = kqd_all + stage*B6;
    #pragma unroll
    for (int i=0;i<6;i++) kqd_out[b*6+i] = a[i];

    if (stage < 3){
      const float* o = obs + b*12;
      unsigned mask = 0;
      #pragma unroll
      for (int i=0;i<6;i++){
        float q0=o[i], qd0=o[6+i];
        float q, qd;
        if (stage == 0){
          q  = q0 + 0.5f*DT*qd0;
          qd = qd0 + 0.5f*DT*a[i];
        } else if (stage == 1){
          float k1 = kqd_all[b*6+i];
          q  = q0 + 0.5f*DT*qd0 + 0.25f*DT*DT*k1;
          qd = qd0 + 0.5f*DT*a[i];
        } else {
          float k2 = kqd_all[B6 + b*6+i];
          q  = q0 + DT*qd0 + 0.5f*DT*DT*k2;
          qd = qd0 + DT*a[i];
        }
        q_cur[b*6+i]=q; qd_cur[b*6+i]=qd;
        float lo = c_LOWER[i]+0.1f, up = c_UPPER[i]-0.1f;
        if (q <= lo || q >= up) mask |= (1u<<i);
      }
      if (mask) atomicOr(viol + stage + 1, (int)mask);
    }

    if (fold_final){
      const float* o = obs + b*12;
      float* po = out + b*12;
      #pragma unroll
      for (int i=0;i<6;i++){
        float q0=o[i], qd0=o[6+i];
        float k1=kqd_all[b*6+i], k2=kqd_all[B6+b*6+i], k3=kqd_all[2*B6+b*6+i];
        float qn = q0 + DT*qd0 + (DT*DT/6.0f)*(k1+k2+k3);
        qn = fminf(fmaxf(qn, c_LOWER[i]), c_UPPER[i]);
        po[i] = qn;
        po[6+i] = qd0 + (DT/6.0f)*(k1 + 2.0f*k2 + 2.0f*k3 + a[i]);
      }
    }
  }
  #undef Bact
}

// ---------------- fallback per-stage kernel --------------------------------
__global__ void __launch_bounds__(256) k_accel(
    int stage, int fold_final,
    const float* __restrict__ obs,
    float* __restrict__ q_cur, float* __restrict__ qd_cur,
    const float* __restrict__ action,
    const float* __restrict__ W1LT, const float* __restrict__ b1L,
    const float* __restrict__ b2L,  const float* __restrict__ b3Lp,
    const float* __restrict__ W1VT, const float* __restrict__ b1V,
    const float* __restrict__ b2V,  const float* __restrict__ W3V,
    const float* __restrict__ W1V,
    const _Float16* __restrict__ fragHi, const _Float16* __restrict__ fragLo,
    int* __restrict__ viol,
    float* __restrict__ kqd_all,
    float* __restrict__ out)
{
  accel_body(stage, fold_final != 0, obs, q_cur, qd_cur, action, W1LT, b1L,
             b2L, b3Lp, W1VT, b1V, b2V, W3V, W1V, fragHi, fragLo, viol,
             kqd_all, out);
}

// ---------------- fused ACCEL-ONLY cooperative kernel ----------------------
// r9: contains ONLY the 4-stage loop (initpre stays a separate launch), so
// regalloc matches the standalone k_accel (~88 VGPR << 128) and the
// 4-blocks/CU residency check should certify. Plain __launch_bounds__(256)
// (r2: min-waves clamp => spill disaster). Host-side gate (r4-validated)
// prevents a failing launch inside graph capture.
__global__ void __launch_bounds__(256) k_fused_accel(
    const float* __restrict__ obs, const float* __restrict__ action,
    const float* __restrict__ W1LT, const float* __restrict__ b1L,
    const float* __restrict__ b2L,  const float* __restrict__ b3Lp,
    const float* __restrict__ W1VT, const float* __restrict__ b1V,
    const float* __restrict__ b2V,  const float* __restrict__ W3V,
    const float* __restrict__ W1V,
    const _Float16* __restrict__ fragHi, const _Float16* __restrict__ fragLo,
    float* __restrict__ q_cur, float* __restrict__ qd_cur,
    float* __restrict__ kqd_all, int* __restrict__ viol, float* __restrict__ out)
{
  cooperative_groups::grid_group grid = cooperative_groups::this_grid();

  // stages 0..3; grid sync between stages (viol[s+1] is batch-global OR,
  // q_cur/qd_cur are cross-block). unroll 1: single body copy for regalloc.
  #pragma unroll 1
  for (int stage = 0; stage < 4; ++stage){
    accel_body(stage, stage==3, obs, q_cur, qd_cur, action, W1LT, b1L, b2L,
               b3Lp, W1VT, b1V, b2V, W3V, W1V, fragHi, fragLo, viol, kqd_all, out);
    if (stage < 3){
      __threadfence();
      grid.sync();
    }
  }
}

extern "C" void kernel_launch(void* const* d_in, const int* in_sizes, int n_in,
                              void* d_out, int out_size, void* d_ws, size_t ws_size,
                              hipStream_t stream) {
  const float* obs    = (const float*)d_in[0];
  const float* action = (const float*)d_in[1];
  const float* W1L = (const float*)d_in[2];  const float* b1L = (const float*)d_in[3];
  const float* W2L = (const float*)d_in[4];  const float* b2L = (const float*)d_in[5];
  const float* W3L = (const float*)d_in[6];  const float* b3L = (const float*)d_in[7];
  const float* W1V = (const float*)d_in[8];  const float* b1V = (const float*)d_in[9];
  const float* W2V = (const float*)d_in[10]; const float* b2V = (const float*)d_in[11];
  const float* W3V = (const float*)d_in[12]; // b3V unused: only grad of V needed

  float* ws = (float*)d_ws;
  _Float16* fragHi = (_Float16*)ws;            // 55296 halves
  _Float16* fragLo = fragHi + 55296;           // 55296 halves
  float* W1LT  = ws + 55296;                   // 1536
  float* W1VT  = W1LT + 1536;                  // 1536
  float* b3Lp  = W1VT + 1536;                  // 32
  float* q_cur  = b3Lp + 32;                   // B6
  float* qd_cur = q_cur + B6;                  // B6
  float* kqd    = qd_cur + B6;                 // 4*B6
  int*   viol   = (int*)(kqd + 4*B6);

  float* out = (float*)d_out;

  // capture-safe path decision: pure driver queries, cached once (r4 lesson:
  // a FAILING coop launch inside graph capture poisons the capture).
  static int coop_ok = -1;
  if (coop_ok < 0){
    int nblk = 0, ncu = 0;
    hipError_t qe = hipOccupancyMaxActiveBlocksPerMultiprocessor(&nblk, (const void*)k_fused_accel, 256, 0);
    hipError_t de = hipDeviceGetAttribute(&ncu, hipDeviceAttributeMultiprocessorCount, 0);
    coop_ok = (qe == hipSuccess && de == hipSuccess && (long)nblk * (long)ncu >= 1024) ? 1 : 0;
  }

  // viol[0] must be zero before the init kernel's atomicOr (both paths)
  hipMemsetAsync(viol, 0, sizeof(int), stream);
  k_initpre<<<64,256,0,stream>>>(W1L, W2L, W3L, W1V, W2V, b3L, obs,
                                 W1LT, W1VT, b3Lp, fragHi, fragLo,
                                 q_cur, qd_cur, viol);

  bool launched = false;
  if (coop_ok == 1){
    void* kargs[] = {
      (void*)&obs, (void*)&action,
      (void*)&W1LT, (void*)&b1L, (void*)&b2L, (void*)&b3Lp,
      (void*)&W1VT, (void*)&b1V, (void*)&b2V, (void*)&W3V, (void*)&W1V,
      (void*)&fragHi, (void*)&fragLo,
      (void*)&q_cur, (void*)&qd_cur, (void*)&kqd, (void*)&viol, (void*)&out
    };
    hipError_t e = hipLaunchCooperativeKernel((const void*)k_fused_accel,
        dim3(1024), dim3(256), kargs, 0, stream);
    if (e == hipSuccess){
      launched = true;
    } else {
      (void)hipGetLastError();
      coop_ok = 0;
    }
  }

  if (!launched){
    for (int s=0; s<4; ++s){
      k_accel<<<1024,256,0,stream>>>(s, (s==3)?1:0, obs, q_cur, qd_cur, action,
          W1LT, b1L, b2L, b3Lp, W1VT, b1V, b2V, W3V, W1V,
          fragHi, fragLo, viol, kqd, out);
    }
  }
}

// Round 10
// 232.401 us; speedup vs baseline: 1.0983x; 1.0915x over previous
//
#include <hip/hip_runtime.h>
#include <math.h>

#define BATCH 16384
#define B6 (BATCH*6)
#define DT 0.01f

using half8_t = __attribute__((ext_vector_type(8))) _Float16;
using half4_t = __attribute__((ext_vector_type(4))) _Float16;
using half2_t = __attribute__((ext_vector_type(2))) _Float16;
using f32x4   = __attribute__((ext_vector_type(4))) float;

__device__ __constant__ float c_LOWER[6]  = {-6.28f,-6.28f,-3.14f,-6.28f,-6.28f,-6.28f};
__device__ __constant__ float c_UPPER[6]  = { 6.28f, 6.28f, 3.14f, 6.28f, 6.28f, 6.28f};
__device__ __constant__ float c_EFFORT[6] = {150.0f,150.0f,150.0f,28.0f,28.0f,28.0f};
__device__ __constant__ int   c_ROWOFF[6] = {0,1,3,6,10,15};

__device__ __forceinline__ float sp_f(float z){
  return fmaxf(z,0.0f) + __logf(1.0f + __expf(-fabsf(z)));
}
__device__ __forceinline__ float sig_f(float z){
  return __builtin_amdgcn_rcpf(1.0f + __expf(-z));
}
// fused softplus+sigmoid sharing one exp (correctness-proven r6/r7)
__device__ __forceinline__ void spsig_f(float z, float& sp, float& sg){
  float e = __expf(-fabsf(z));
  float t = 1.0f + e;
  float r = __builtin_amdgcn_rcpf(t);
  sp = fmaxf(z,0.0f) + __logf(t);
  sg = (z >= 0.0f) ? r : e*r;
}

__device__ __forceinline__ float4 f4all(float v){ return make_float4(v,v,v,v); }
__device__ __forceinline__ void fma4(float4& acc, float w, float4 a){
  acc.x=fmaf(w,a.x,acc.x); acc.y=fmaf(w,a.y,acc.y); acc.z=fmaf(w,a.z,acc.z); acc.w=fmaf(w,a.w,acc.w);
}

// XOR-swizzled accessors for sh_t [12][16]
__device__ __forceinline__ const float4* chunkc(const float (*arr)[16], int n, int cc){
  return reinterpret_cast<const float4*>(&arr[n][4*(cc ^ ((n>>1)&3))]);
}
__device__ __forceinline__ float& el(float (*arr)[16], int n, int s){
  return arr[n][4*((s>>2) ^ ((n>>1)&3)) + (s&3)];
}

// ---- MFMA helpers --------------------------------------------------------
__device__ __forceinline__ f32x4 mfma3(half8_t ah, half8_t al, half8_t bh, half8_t bl, f32x4 acc){
  acc = __builtin_amdgcn_mfma_f32_16x16x32_f16(ah, bh, acc, 0,0,0);
  acc = __builtin_amdgcn_mfma_f32_16x16x32_f16(ah, bl, acc, 0,0,0);
  acc = __builtin_amdgcn_mfma_f32_16x16x32_f16(al, bh, acc, 0,0,0);
  return acc;
}
__device__ __forceinline__ f32x4 mfma1(half8_t ah, half8_t bh, f32x4 acc){
  return __builtin_amdgcn_mfma_f32_16x16x32_f16(ah, bh, acc, 0,0,0);
}
__device__ __forceinline__ half8_t ldB(const _Float16 (*B)[136], int n, int q, int quad){
  return *reinterpret_cast<const half8_t*>(&B[n][q*32 + quad*8]);
}
__device__ __forceinline__ void stB4(_Float16 (*Bh)[136], _Float16 (*Bl)[136], int n, int base, float4 v){
  half4_t hi, lo;
  const float* p = &v.x;
  #pragma unroll
  for (int j=0;j<4;j++){ hi[j] = (_Float16)p[j]; lo[j] = (_Float16)(p[j] - (float)hi[j]); }
  *reinterpret_cast<half4_t*>(&Bh[n][base]) = hi;
  *reinterpret_cast<half4_t*>(&Bl[n][base]) = lo;
}
__device__ __forceinline__ void stB2(_Float16 (*Bh)[136], _Float16 (*Bl)[136], int n, int k2, float a, float b){
  half2_t hi, lo;
  hi[0]=(_Float16)a; hi[1]=(_Float16)b;
  lo[0]=(_Float16)(a-(float)hi[0]); lo[1]=(_Float16)(b-(float)hi[1]);
  *reinterpret_cast<half2_t*>(&Bh[n][k2]) = hi;
  *reinterpret_cast<half2_t*>(&Bl[n][k2]) = lo;
}
// plain-fp16 stores (tangent path r7; V-net path r10 — precision-safe:
// gravity enters rhs additively, err ~1e-3*|g| << tau O(150))
__device__ __forceinline__ void stH2(_Float16 (*Bh)[136], int n, int k2, float a, float b){
  half2_t hi; hi[0]=(_Float16)a; hi[1]=(_Float16)b;
  *reinterpret_cast<half2_t*>(&Bh[n][k2]) = hi;
}
__device__ __forceinline__ void stH4(_Float16 (*Bh)[136], int n, int base, float4 v){
  half4_t hi;
  #pragma unroll
  for (int j=0;j<4;j++) hi[j] = (_Float16)(&v.x)[j];
  *reinterpret_cast<half4_t*>(&Bh[n][base]) = hi;
}

// ---------------- merged init + stage-0 pre --------------------------------
// viol[0] zeroed by hipMemsetAsync before this kernel (capture-legal).
__global__ void __launch_bounds__(256) k_initpre(
    const float* __restrict__ W1L, const float* __restrict__ W2L,
    const float* __restrict__ W3L, const float* __restrict__ W1V,
    const float* __restrict__ W2V, const float* __restrict__ b3L,
    const float* __restrict__ obs,
    float* __restrict__ W1LT, float* __restrict__ W1VT, float* __restrict__ b3Lp,
    _Float16* __restrict__ fragHi, _Float16* __restrict__ fragLo,
    float* __restrict__ q_cur, float* __restrict__ qd_cur, int* __restrict__ viol)
{
  int t = blockIdx.x*256 + threadIdx.x;
  if (t >= 1 && t < 4) viol[t] = 0;
  if (t < 1536){ int i = t/128, k = t%128; W1LT[t] = W1L[k*12+i]; W1VT[t] = W1V[k*12+i]; }
  if (t < 32) b3Lp[t] = (t < 21) ? b3L[t] : 0.0f;
  if (t < 6912){
    int kind, f;
    if (t < 2048){ kind=0; f=t; }
    else if (t < 4096){ kind=1; f=t-2048; }
    else if (t < 6144){ kind=2; f=t-4096; }
    else if (t < 6656){ kind=3; f=t-6144; }
    else { kind=4; f=t-6656; }
    int tile = f>>8, q = (f>>6)&3, l = f&63, m = l&15, kq = 8*(l>>4);
    int off = (kind==0?0:kind==1?16384:kind==2?32768:kind==3?49152:53248) + f*8;
    #pragma unroll
    for (int e=0;e<8;e++){
      float v;
      int kk = 32*q + kq + e;
      if (kind==0)      v = W2L[(16*tile+m)*128 + kk];
      else if (kind==1) v = W2V[(16*tile+m)*128 + kk];
      else if (kind==2) v = W2V[kk*128 + (16*tile+m)];
      else if (kind==3){ int r = 16*tile+m; v = (r<21) ? W3L[r*128 + kk] : 0.0f; }
      else              v = (m<12) ? W1V[kk*12 + m] : 0.0f;
      _Float16 hi = (_Float16)v;
      _Float16 lo = (_Float16)(v - (float)hi);
      fragHi[off+e] = hi; fragLo[off+e] = lo;
    }
  }
  if (t < BATCH){
    const float* o = obs + t*12;
    unsigned mask = 0;
    #pragma unroll
    for (int i=0;i<6;i++){
      float q = o[i];
      q_cur[t*6+i]=q; qd_cur[t*6+i]=o[6+i];
      float lo = c_LOWER[i]+0.1f, up = c_UPPER[i]-0.1f;
      if (q <= lo || q >= up) mask |= (1u<<i);
    }
    unsigned wm = 0;
    #pragma unroll
    for (int i=0;i<6;i++) if (__ballot((int)((mask>>i)&1u))) wm |= (1u<<i);
    if ((threadIdx.x & 63)==0 && wm) atomicOr(viol, (int)wm);
  }
}

// ---------------- heavy per-stage accel (MFMA) -----------------------------
// 16 samples/block, 256 threads (4 waves), 1024 blocks.
// r10: V-net path (L2V / V-bwd / dV) dropped from split-fp16 to PLAIN fp16
// (mfma1, hi buffer only) — gravity enters rhs additively so ~1e-3 rel err
// on g is ~1e-4 on outputs. Mass-L path stays split (feeds the solve matrix).
// Cooperative machinery removed: r1-vs-r5-vs-r7 overhead comparison shows
// launch-boundary cost is ~fixed (~45us harness), so fusion had no payoff.
__global__ void __launch_bounds__(256) k_accel(
    int stage, int fold_final,
    const float* __restrict__ obs,
    float* __restrict__ q_cur, float* __restrict__ qd_cur,
    const float* __restrict__ action,
    const float* __restrict__ W1LT, const float* __restrict__ b1L,
    const float* __restrict__ b2L,  const float* __restrict__ b3Lp,
    const float* __restrict__ W1VT, const float* __restrict__ b1V,
    const float* __restrict__ b2V,  const float* __restrict__ W3V,
    const float* __restrict__ W1V,
    const _Float16* __restrict__ fragHi, const _Float16* __restrict__ fragLo,
    int* __restrict__ viol,
    float* __restrict__ kqd_all,
    float* __restrict__ out)
{
  // Bd[0] doubles as Bact (lifetime-disjoint; V-bwd alias covered by barrier)
  __shared__ alignas(16) _Float16 Bd[2][2][16][136];
  #define Bact Bd[0]
  __shared__ alignas(16) float sh_t[12][16];
  __shared__ float sh_y[21][17], sh_s3[21][17], sh_dy[42][17], sh_dv[12][17];
  __shared__ float sh_wg[2][6][16];
  __shared__ float sh_qd[6][16], sh_tau[6][16], sh_f[6][16];
  __shared__ float sh_c[6][16], sh_grav[6][16], sh_v[6][16];

  const int tid = threadIdx.x;
  const int l = tid & 63;
  const int w = tid >> 6;
  const int lane_n = l & 15;
  const int quad = l >> 4;
  const int base0 = w*16 + quad*4;
  const int base1 = (w+4)*16 + quad*4;
  const int s0 = blockIdx.x * 16;
  const int vm = viol[stage];

  const half8_t* fW2Lh  = (const half8_t*)(fragHi);
  const half8_t* fW2Ll  = (const half8_t*)(fragLo);
  const half8_t* fW2Vh  = (const half8_t*)(fragHi + 16384);
  const half8_t* fW2VTh = (const half8_t*)(fragHi + 32768);
  const half8_t* fW3h   = (const half8_t*)(fragHi + 49152);
  const half8_t* fW3l   = (const half8_t*)(fragLo + 49152);
  const half8_t* fW1Th  = (const half8_t*)(fragHi + 53248);

  // ---- phase 0: tile load, trig, tau, constraint force
  if (tid < 96){
    int s = tid & 15, i = tid >> 4;
    float q  = q_cur [(s0+s)*6 + i];
    float qd = qd_cur[(s0+s)*6 + i];
    sh_qd[i][s]=qd;
    sh_tau[i][s] = action[(s0+s)*6+i] * c_EFFORT[i];
    el(sh_t, 2*i,   s) = cosf(q);
    el(sh_t, 2*i+1, s) = sinf(q);
    float lo = c_LOWER[i]+0.1f, up = c_UPPER[i]-0.1f;
    float barrier = -5.0f*(1.0f/(q-lo) - 1.0f/(up-q));
    float clip = (q<=lo)? c_EFFORT[i] : ((q>=up)? -c_EFFORT[i] : 0.0f);
    sh_f[i][s] = ((vm>>i)&1) ? clip : barrier;
    sh_c[i][s] = 0.0f;
  }
  __syncthreads();

  float4 s1a, s1b;
  // ---- L1L (VALU) -> Bact (split fp16: feeds mass-L path)
  {
    float2 bb = *reinterpret_cast<const float2*>(b1L + 2*l);
    float4 z0 = f4all(bb.x), z1 = f4all(bb.y);
    #pragma unroll
    for (int i=0;i<12;i++){
      float2 wv = *reinterpret_cast<const float2*>(W1LT + i*128 + 2*l);
      float4 a = *chunkc(sh_t, i, w);
      fma4(z0, wv.x, a); fma4(z1, wv.y, a);
    }
    float4 h0, h1;
    #pragma unroll
    for (int j=0;j<4;j++){
      spsig_f((&z0.x)[j], (&h0.x)[j], (&s1a.x)[j]);
      spsig_f((&z1.x)[j], (&h1.x)[j], (&s1b.x)[j]);
    }
    #pragma unroll
    for (int j=0;j<4;j++)
      stB2(Bact[0], Bact[1], 4*w+j, 2*l, (&h0.x)[j], (&h1.x)[j]);
  }
  __syncthreads();

  float4 s2a, s2b;
  // ---- L2L MFMA + epilogue (h2 -> Bact in-place)
  {
    f32x4 acc0 = {0.f,0.f,0.f,0.f}, acc1 = {0.f,0.f,0.f,0.f};
    #pragma unroll
    for (int q=0;q<4;q++){
      half8_t bh = ldB(Bact[0], lane_n, q, quad);
      half8_t bl = ldB(Bact[1], lane_n, q, quad);
      acc0 = mfma3(fW2Lh[(w*4+q)*64+l],     fW2Ll[(w*4+q)*64+l],     bh, bl, acc0);
      acc1 = mfma3(fW2Lh[((w+4)*4+q)*64+l], fW2Ll[((w+4)*4+q)*64+l], bh, bl, acc1);
    }
    __syncthreads();
    float4 ba = *reinterpret_cast<const float4*>(b2L + base0);
    float4 bb = *reinterpret_cast<const float4*>(b2L + base1);
    float4 h2a, h2b;
    #pragma unroll
    for (int j=0;j<4;j++){
      spsig_f(acc0[j] + (&ba.x)[j], (&h2a.x)[j], (&s2a.x)[j]);
      spsig_f(acc1[j] + (&bb.x)[j], (&h2b.x)[j], (&s2b.x)[j]);
    }
    stB4(Bact[0], Bact[1], lane_n, base0, h2a);
    stB4(Bact[0], Bact[1], lane_n, base1, h2b);
  }
  __syncthreads();

  // ---- L3 MFMA (waves 0,1) -> y, s3
  if (w < 2){
    f32x4 acc = {0.f,0.f,0.f,0.f};
    #pragma unroll
    for (int q=0;q<4;q++){
      half8_t bh = ldB(Bact[0], lane_n, q, quad);
      half8_t bl = ldB(Bact[1], lane_n, q, quad);
      acc = mfma3(fW3h[(w*4+q)*64+l], fW3l[(w*4+q)*64+l], bh, bl, acc);
    }
    int rb = w*16 + quad*4;
    #pragma unroll
    for (int j=0;j<4;j++){
      int r = rb + j;
      if (r < 21){
        float z = acc[j] + b3Lp[r];
        float sp, sg;
        spsig_f(z, sp, sg);
        sh_y[r][lane_n]  = sp;
        sh_s3[r][lane_n] = sg;
      }
    }
  }
  __syncthreads();
  // (Bact dead: sh_y/sh_s3 captured. Bd[0] free for tangents.)

  // ---- v = L^T qdot
  if (tid < 96){
    int s = tid & 15, jj = tid >> 4;
    float acc = 0.f;
    for (int i=jj;i<6;i++) acc = fmaf(sh_y[c_ROWOFF[i]+jj][s], sh_qd[i][s], acc);
    sh_v[jj][s] = acc;
  }

  // ---- tangent groups: dirs {2G, 2G+1} — plain fp16 path (r7)
  for (int G=0; G<3; ++G){
    #pragma unroll
    for (int d=0; d<2; ++d){
      int g = 2*G + d;
      float2 w0 = *reinterpret_cast<const float2*>(W1LT + (2*g)*128 + 2*l);
      float2 w1 = *reinterpret_cast<const float2*>(W1LT + (2*g+1)*128 + 2*l);
      float4 tc = *chunkc(sh_t, 2*g,   w);
      float4 ts = *chunkc(sh_t, 2*g+1, w);
      #pragma unroll
      for (int j=0;j<4;j++){
        float tcj = (&tc.x)[j], tsj = (&ts.x)[j];
        float d0 = (&s1a.x)[j]*(tcj*w1.x - tsj*w0.x);
        float d1 = (&s1b.x)[j]*(tcj*w1.y - tsj*w0.y);
        stH2(Bd[d][0], 4*w+j, 2*l, d0, d1);
      }
    }
    __syncthreads();
    f32x4 ta00={0.f,0.f,0.f,0.f}, ta01=ta00, ta10=ta00, ta11=ta00;
    #pragma unroll
    for (int q=0;q<4;q++){
      half8_t b0h = ldB(Bd[0][0], lane_n, q, quad);
      half8_t b1h = ldB(Bd[1][0], lane_n, q, quad);
      half8_t a0h = fW2Lh[(w*4+q)*64+l];
      half8_t a1h = fW2Lh[((w+4)*4+q)*64+l];
      ta00 = mfma1(a0h, b0h, ta00);
      ta01 = mfma1(a0h, b1h, ta01);
      ta10 = mfma1(a1h, b0h, ta10);
      ta11 = mfma1(a1h, b1h, ta11);
    }
    __syncthreads();
    {
      float4 v;
      #pragma unroll
      for (int j=0;j<4;j++) (&v.x)[j] = (&s2a.x)[j]*ta00[j];
      stH4(Bd[0][0], lane_n, base0, v);
      #pragma unroll
      for (int j=0;j<4;j++) (&v.x)[j] = (&s2b.x)[j]*ta10[j];
      stH4(Bd[0][0], lane_n, base1, v);
      #pragma unroll
      for (int j=0;j<4;j++) (&v.x)[j] = (&s2a.x)[j]*ta01[j];
      stH4(Bd[1][0], lane_n, base0, v);
      #pragma unroll
      for (int j=0;j<4;j++) (&v.x)[j] = (&s2b.x)[j]*ta11[j];
      stH4(Bd[1][0], lane_n, base1, v);
    }
    __syncthreads();
    {
      int d = w & 1, tt = w >> 1;
      f32x4 acc = {0.f,0.f,0.f,0.f};
      #pragma unroll
      for (int q=0;q<4;q++){
        half8_t bh = ldB(Bd[d][0], lane_n, q, quad);
        acc = mfma1(fW3h[(tt*4+q)*64+l], bh, acc);
      }
      int rb = tt*16 + quad*4;
      #pragma unroll
      for (int j=0;j<4;j++){
        int r = rb + j;
        if (r < 21) sh_dy[d*21 + r][lane_n] = sh_s3[r][lane_n] * acc[j];
      }
    }
    __syncthreads();
    if (tid < 32){
      int s = tid & 15, gg = tid >> 4;
      float qd[6];
      #pragma unroll
      for (int i=0;i<6;i++) qd[i] = sh_qd[i][s];
      float u[6];
      #pragma unroll
      for (int jj=0;jj<6;jj++){
        float acc = 0.f;
        for (int i=jj;i<6;i++) acc = fmaf(sh_dy[gg*21 + c_ROWOFF[i]+jj][s], qd[i], acc);
        u[jj] = acc;
      }
      #pragma unroll
      for (int i=0;i<6;i++){
        float acc = 0.f;
        for (int j=0;j<=i;j++){
          acc = fmaf(sh_dy[gg*21 + c_ROWOFF[i]+j][s], sh_v[j][s], acc);
          acc = fmaf(sh_y [c_ROWOFF[i]+j][s], u[j], acc);
        }
        sh_wg[gg][i][s] = acc;
      }
    }
    __syncthreads();
    if (tid < 96){
      int s = tid & 15, i = tid >> 4;
      float acc = sh_c[i][s];
      acc = fmaf(sh_qd[2*G][s],   sh_wg[0][i][s], acc);
      acc = fmaf(sh_qd[2*G+1][s], sh_wg[1][i][s], acc);
      int gi = i - 2*G;
      if (gi == 0 || gi == 1){
        float r = 0.f;
        #pragma unroll
        for (int j=0;j<6;j++) r = fmaf(sh_qd[j][s], sh_wg[gi][j][s], r);
        acc -= 0.5f*r;
      }
      sh_c[i][s] = acc;
    }
    __syncthreads();
  }

  // ---- V-net L1 (VALU) -> Bact (r10: plain fp16, hi buffer only)
  {
    float2 bb = *reinterpret_cast<const float2*>(b1V + 2*l);
    float4 z0 = f4all(bb.x), z1 = f4all(bb.y);
    #pragma unroll
    for (int i=0;i<12;i++){
      float2 wv = *reinterpret_cast<const float2*>(W1VT + i*128 + 2*l);
      float4 a = *chunkc(sh_t, i, w);
      fma4(z0, wv.x, a); fma4(z1, wv.y, a);
    }
    #pragma unroll
    for (int j=0;j<4;j++){
      float h0 = sp_f((&z0.x)[j]);
      float h1 = sp_f((&z1.x)[j]);
      stH2(Bact[0], 4*w+j, 2*l, h0, h1);
    }
  }
  __syncthreads();
  // ---- L2V MFMA (plain fp16); epilogue g2 = sig(z)*W3V -> Bact in-place
  {
    f32x4 acc0 = {0.f,0.f,0.f,0.f}, acc1 = {0.f,0.f,0.f,0.f};
    #pragma unroll
    for (int q=0;q<4;q++){
      half8_t bh = ldB(Bact[0], lane_n, q, quad);
      acc0 = mfma1(fW2Vh[(w*4+q)*64+l],     bh, acc0);
      acc1 = mfma1(fW2Vh[((w+4)*4+q)*64+l], bh, acc1);
    }
    __syncthreads();
    float4 ba  = *reinterpret_cast<const float4*>(b2V + base0);
    float4 bb  = *reinterpret_cast<const float4*>(b2V + base1);
    float4 w3a = *reinterpret_cast<const float4*>(W3V + base0);
    float4 w3b = *reinterpret_cast<const float4*>(W3V + base1);
    float4 g2a, g2b;
    #pragma unroll
    for (int j=0;j<4;j++){
      (&g2a.x)[j] = sig_f(acc0[j] + (&ba.x)[j]) * (&w3a.x)[j];
      (&g2b.x)[j] = sig_f(acc1[j] + (&bb.x)[j]) * (&w3b.x)[j];
    }
    stH4(Bact[0], lane_n, base0, g2a);
    stH4(Bact[0], lane_n, base1, g2b);
  }
  __syncthreads();
  // ---- V bwd MFMA (A = W2V^T, plain fp16); epilogue: s1V recompute, g1
  // ALIAS HAZARD: reads Bact[0] (g2), writes g1 to same buffer; barrier
  // below orders all reads before any write.
  {
    f32x4 acc0 = {0.f,0.f,0.f,0.f}, acc1 = {0.f,0.f,0.f,0.f};
    #pragma unroll
    for (int q=0;q<4;q++){
      half8_t bh = ldB(Bact[0], lane_n, q, quad);
      acc0 = mfma1(fW2VTh[(w*4+q)*64+l],     bh, acc0);
      acc1 = mfma1(fW2VTh[((w+4)*4+q)*64+l], bh, acc1);
    }
    float tn[12];
    #pragma unroll
    for (int i=0;i<12;i++) tn[i] = el(sh_t, i, lane_n);
    float4 g1a, g1b;
    #pragma unroll
    for (int j=0;j<4;j++){
      int r = base0 + j;
      float z = b1V[r];
      const float* wr = W1V + r*12;
      #pragma unroll
      for (int i=0;i<12;i++) z = fmaf(wr[i], tn[i], z);
      (&g1a.x)[j] = sig_f(z) * acc0[j];
      r = base1 + j;
      z = b1V[r];
      wr = W1V + r*12;
      #pragma unroll
      for (int i=0;i<12;i++) z = fmaf(wr[i], tn[i], z);
      (&g1b.x)[j] = sig_f(z) * acc1[j];
    }
    __syncthreads();   // all g2 reads complete before g1 overwrite (alias)
    stH4(Bact[0], lane_n, base0, g1a);
    stH4(Bact[0], lane_n, base1, g1b);
  }
  __syncthreads();
  // ---- dV/dt = W1V^T g1 via MFMA (wave 0 only; plain fp16)
  if (w == 0){
    f32x4 acc = {0.f,0.f,0.f,0.f};
    #pragma unroll
    for (int q=0;q<4;q++){
      half8_t bh = ldB(Bact[0], lane_n, q, quad);
      acc = mfma1(fW1Th[q*64+l], bh, acc);
    }
    int rb = quad*4;
    #pragma unroll
    for (int j=0;j<4;j++){
      int r = rb + j;
      if (r < 12) sh_dv[r][lane_n] = acc[j];
    }
  }
  __syncthreads();
  // ---- gravity
  if (tid < 96){
    int k = tid>>4, s = tid&15;
    sh_grav[k][s] = fmaf(el(sh_t,2*k,s), sh_dv[2*k+1][s],
                         -(el(sh_t,2*k+1,s)*sh_dv[2*k][s]));
  }
  __syncthreads();
  // ---- assembly + triangular solves + folded next-stage pre (+ final)
  if (l < 4){
    int s = w*4 + l;
    float Lm[21];
    #pragma unroll
    for (int o=0;o<21;o++) Lm[o] = sh_y[o][s];
    float rhs[6];
    #pragma unroll
    for (int i=0;i<6;i++) rhs[i] = sh_tau[i][s] - sh_c[i][s] - sh_grav[i][s] - sh_f[i][s];
    float z[6];
    #pragma unroll
    for (int i=0;i<6;i++){
      float acc = rhs[i];
      for (int j=0;j<i;j++) acc = fmaf(-Lm[c_ROWOFF[i]+j], z[j], acc);
      z[i] = acc * __builtin_amdgcn_rcpf(Lm[c_ROWOFF[i]+i]);
    }
    float a[6];
    #pragma unroll
    for (int i=5;i>=0;i--){
      float acc = z[i];
      for (int j=i+1;j<6;j++) acc = fmaf(-Lm[c_ROWOFF[j]+i], a[j], acc);
      a[i] = acc * __builtin_amdgcn_rcpf(Lm[c_ROWOFF[i]+i]);
    }
    int b = s0 + s;
    float* kqd_out = kqd_all + stage*B6;
    #pragma unroll
    for (int i=0;i<6;i++) kqd_out[b*6+i] = a[i];

    if (stage < 3){
      const float* o = obs + b*12;
      unsigned mask = 0;
      #pragma unroll
      for (int i=0;i<6;i++){
        float q0=o[i], qd0=o[6+i];
        float q, qd;
        if (stage == 0){
          q  = q0 + 0.5f*DT*qd0;
          qd = qd0 + 0.5f*DT*a[i];
        } else if (stage == 1){
          float k1 = kqd_all[b*6+i];
          q  = q0 + 0.5f*DT*qd0 + 0.25f*DT*DT*k1;
          qd = qd0 + 0.5f*DT*a[i];
        } else {
          float k2 = kqd_all[B6 + b*6+i];
          q  = q0 + DT*qd0 + 0.5f*DT*DT*k2;
          qd = qd0 + DT*a[i];
        }
        q_cur[b*6+i]=q; qd_cur[b*6+i]=qd;
        float lo = c_LOWER[i]+0.1f, up = c_UPPER[i]-0.1f;
        if (q <= lo || q >= up) mask |= (1u<<i);
      }
      if (mask) atomicOr(viol + stage + 1, (int)mask);
    }

    if (fold_final){
      const float* o = obs + b*12;
      float* po = out + b*12;
      #pragma unroll
      for (int i=0;i<6;i++){
        float q0=o[i], qd0=o[6+i];
        float k1=kqd_all[b*6+i], k2=kqd_all[B6+b*6+i], k3=kqd_all[2*B6+b*6+i];
        float qn = q0 + DT*qd0 + (DT*DT/6.0f)*(k1+k2+k3);
        qn = fminf(fmaxf(qn, c_LOWER[i]), c_UPPER[i]);
        po[i] = qn;
        po[6+i] = qd0 + (DT/6.0f)*(k1 + 2.0f*k2 + 2.0f*k3 + a[i]);
      }
    }
  }
  #undef Bact
}

extern "C" void kernel_launch(void* const* d_in, const int* in_sizes, int n_in,
                              void* d_out, int out_size, void* d_ws, size_t ws_size,
                              hipStream_t stream) {
  const float* obs    = (const float*)d_in[0];
  const float* action = (const float*)d_in[1];
  const float* W1L = (const float*)d_in[2];  const float* b1L = (const float*)d_in[3];
  const float* W2L = (const float*)d_in[4];  const float* b2L = (const float*)d_in[5];
  const float* W3L = (const float*)d_in[6];  const float* b3L = (const float*)d_in[7];
  const float* W1V = (const float*)d_in[8];  const float* b1V = (const float*)d_in[9];
  const float* W2V = (const float*)d_in[10]; const float* b2V = (const float*)d_in[11];
  const float* W3V = (const float*)d_in[12]; // b3V unused: only grad of V needed

  float* ws = (float*)d_ws;
  _Float16* fragHi = (_Float16*)ws;            // 55296 halves
  _Float16* fragLo = fragHi + 55296;           // 55296 halves
  float* W1LT  = ws + 55296;                   // 1536
  float* W1VT  = W1LT + 1536;                  // 1536
  float* b3Lp  = W1VT + 1536;                  // 32
  float* q_cur  = b3Lp + 32;                   // B6
  float* qd_cur = q_cur + B6;                  // B6
  float* kqd    = qd_cur + B6;                 // 4*B6
  int*   viol   = (int*)(kqd + 4*B6);

  float* out = (float*)d_out;

  hipMemsetAsync(viol, 0, sizeof(int), stream);
  k_initpre<<<64,256,0,stream>>>(W1L, W2L, W3L, W1V, W2V, b3L, obs,
                                 W1LT, W1VT, b3Lp, fragHi, fragLo,
                                 q_cur, qd_cur, viol);
  for (int s=0; s<4; ++s){
    k_accel<<<1024,256,0,stream>>>(s, (s==3)?1:0, obs, q_cur, qd_cur, action,
        W1LT, b1L, b2L, b3Lp, W1VT, b1V, b2V, W3V, W1V,
        fragHi, fragLo, viol, kqd, out);
  }
}

// Round 11
// 229.283 us; speedup vs baseline: 1.1133x; 1.0136x over previous
//
#include <hip/hip_runtime.h>
#include <math.h>

#define BATCH 16384
#define B6 (BATCH*6)
#define DT 0.01f

using half8_t = __attribute__((ext_vector_type(8))) _Float16;
using half4_t = __attribute__((ext_vector_type(4))) _Float16;
using half2_t = __attribute__((ext_vector_type(2))) _Float16;
using f32x4   = __attribute__((ext_vector_type(4))) float;

__device__ __constant__ float c_LOWER[6]  = {-6.28f,-6.28f,-3.14f,-6.28f,-6.28f,-6.28f};
__device__ __constant__ float c_UPPER[6]  = { 6.28f, 6.28f, 3.14f, 6.28f, 6.28f, 6.28f};
__device__ __constant__ float c_EFFORT[6] = {150.0f,150.0f,150.0f,28.0f,28.0f,28.0f};
__device__ __constant__ int   c_ROWOFF[6] = {0,1,3,6,10,15};

__device__ __forceinline__ float sp_f(float z){
  return fmaxf(z,0.0f) + __logf(1.0f + __expf(-fabsf(z)));
}
__device__ __forceinline__ float sig_f(float z){
  return __builtin_amdgcn_rcpf(1.0f + __expf(-z));
}
// fused softplus+sigmoid sharing one exp (correctness-proven r6/r7)
__device__ __forceinline__ void spsig_f(float z, float& sp, float& sg){
  float e = __expf(-fabsf(z));
  float t = 1.0f + e;
  float r = __builtin_amdgcn_rcpf(t);
  sp = fmaxf(z,0.0f) + __logf(t);
  sg = (z >= 0.0f) ? r : e*r;
}

__device__ __forceinline__ float4 f4all(float v){ return make_float4(v,v,v,v); }
__device__ __forceinline__ void fma4(float4& acc, float w, float4 a){
  acc.x=fmaf(w,a.x,acc.x); acc.y=fmaf(w,a.y,acc.y); acc.z=fmaf(w,a.z,acc.z); acc.w=fmaf(w,a.w,acc.w);
}

// XOR-swizzled accessors for sh_t [12][16]
__device__ __forceinline__ const float4* chunkc(const float (*arr)[16], int n, int cc){
  return reinterpret_cast<const float4*>(&arr[n][4*(cc ^ ((n>>1)&3))]);
}
__device__ __forceinline__ float& el(float (*arr)[16], int n, int s){
  return arr[n][4*((s>>2) ^ ((n>>1)&3)) + (s&3)];
}

// ---- MFMA helpers --------------------------------------------------------
// mfma2 (r11): split WEIGHT (ah+al) x plain-fp16 activation bh.
__device__ __forceinline__ f32x4 mfma2(half8_t ah, half8_t al, half8_t bh, f32x4 acc){
  acc = __builtin_amdgcn_mfma_f32_16x16x32_f16(ah, bh, acc, 0,0,0);
  acc = __builtin_amdgcn_mfma_f32_16x16x32_f16(al, bh, acc, 0,0,0);
  return acc;
}
__device__ __forceinline__ f32x4 mfma1(half8_t ah, half8_t bh, f32x4 acc){
  return __builtin_amdgcn_mfma_f32_16x16x32_f16(ah, bh, acc, 0,0,0);
}
__device__ __forceinline__ half8_t ldB(const _Float16 (*B)[136], int n, int q, int quad){
  return *reinterpret_cast<const half8_t*>(&B[n][q*32 + quad*8]);
}
// plain-fp16 stores (tangent r7; V-net r10; L-path activations r11 —
// weight operand stays split so L weights keep ~2^-22; activation fp16
// gives dz ~5e-4 -> dy ~1e-3 -> output ~0.01-0.05 << 0.25 tol)
__device__ __forceinline__ void stH2(_Float16 (*Bh)[136], int n, int k2, float a, float b){
  half2_t hi; hi[0]=(_Float16)a; hi[1]=(_Float16)b;
  *reinterpret_cast<half2_t*>(&Bh[n][k2]) = hi;
}
__device__ __forceinline__ void stH4(_Float16 (*Bh)[136], int n, int base, float4 v){
  half4_t hi;
  #pragma unroll
  for (int j=0;j<4;j++) hi[j] = (_Float16)(&v.x)[j];
  *reinterpret_cast<half4_t*>(&Bh[n][base]) = hi;
}

// ---------------- merged init + stage-0 pre --------------------------------
// viol[0] zeroed by hipMemsetAsync before this kernel (capture-legal).
__global__ void __launch_bounds__(256) k_initpre(
    const float* __restrict__ W1L, const float* __restrict__ W2L,
    const float* __restrict__ W3L, const float* __restrict__ W1V,
    const float* __restrict__ W2V, const float* __restrict__ b3L,
    const float* __restrict__ obs,
    float* __restrict__ W1LT, float* __restrict__ W1VT, float* __restrict__ b3Lp,
    _Float16* __restrict__ fragHi, _Float16* __restrict__ fragLo,
    float* __restrict__ q_cur, float* __restrict__ qd_cur, int* __restrict__ viol)
{
  int t = blockIdx.x*256 + threadIdx.x;
  if (t >= 1 && t < 4) viol[t] = 0;
  if (t < 1536){ int i = t/128, k = t%128; W1LT[t] = W1L[k*12+i]; W1VT[t] = W1V[k*12+i]; }
  if (t < 32) b3Lp[t] = (t < 21) ? b3L[t] : 0.0f;
  if (t < 6912){
    int kind, f;
    if (t < 2048){ kind=0; f=t; }
    else if (t < 4096){ kind=1; f=t-2048; }
    else if (t < 6144){ kind=2; f=t-4096; }
    else if (t < 6656){ kind=3; f=t-6144; }
    else { kind=4; f=t-6656; }
    int tile = f>>8, q = (f>>6)&3, l = f&63, m = l&15, kq = 8*(l>>4);
    int off = (kind==0?0:kind==1?16384:kind==2?32768:kind==3?49152:53248) + f*8;
    #pragma unroll
    for (int e=0;e<8;e++){
      float v;
      int kk = 32*q + kq + e;
      if (kind==0)      v = W2L[(16*tile+m)*128 + kk];
      else if (kind==1) v = W2V[(16*tile+m)*128 + kk];
      else if (kind==2) v = W2V[kk*128 + (16*tile+m)];
      else if (kind==3){ int r = 16*tile+m; v = (r<21) ? W3L[r*128 + kk] : 0.0f; }
      else              v = (m<12) ? W1V[kk*12 + m] : 0.0f;
      _Float16 hi = (_Float16)v;
      _Float16 lo = (_Float16)(v - (float)hi);
      fragHi[off+e] = hi; fragLo[off+e] = lo;
    }
  }
  if (t < BATCH){
    const float* o = obs + t*12;
    unsigned mask = 0;
    #pragma unroll
    for (int i=0;i<6;i++){
      float q = o[i];
      q_cur[t*6+i]=q; qd_cur[t*6+i]=o[6+i];
      float lo = c_LOWER[i]+0.1f, up = c_UPPER[i]-0.1f;
      if (q <= lo || q >= up) mask |= (1u<<i);
    }
    unsigned wm = 0;
    #pragma unroll
    for (int i=0;i<6;i++) if (__ballot((int)((mask>>i)&1u))) wm |= (1u<<i);
    if ((threadIdx.x & 63)==0 && wm) atomicOr(viol, (int)wm);
  }
}

// ---------------- heavy per-stage accel (MFMA) -----------------------------
// 16 samples/block, 256 threads (4 waves), 1024 blocks.
// r11: (a) mass-L activations plain fp16 (mfma2 keeps weight split): L2L
// 24->16 MFMA, L3 12->8, Bact-lo traffic gone from L-path; (b) tangent
// loop-end barrier removed (audit: Bd readers drain at dy-MFMA barrier,
// >=2 barriers separate sh_wg read from next write; stH2 touches only Bd);
// (c) gravity folded into l<4 tail (phase + barrier removed);
// (d) __cosf/__sinf (|q|<=2pi, hw-range-safe).
__global__ void __launch_bounds__(256) k_accel(
    int stage, int fold_final,
    const float* __restrict__ obs,
    float* __restrict__ q_cur, float* __restrict__ qd_cur,
    const float* __restrict__ action,
    const float* __restrict__ W1LT, const float* __restrict__ b1L,
    const float* __restrict__ b2L,  const float* __restrict__ b3Lp,
    const float* __restrict__ W1VT, const float* __restrict__ b1V,
    const float* __restrict__ b2V,  const float* __restrict__ W3V,
    const float* __restrict__ W1V,
    const _Float16* __restrict__ fragHi, const _Float16* __restrict__ fragLo,
    int* __restrict__ viol,
    float* __restrict__ kqd_all,
    float* __restrict__ out)
{
  // Bd[0] doubles as Bact (lifetime-disjoint; V-bwd alias covered by barrier)
  __shared__ alignas(16) _Float16 Bd[2][2][16][136];
  #define Bact Bd[0]
  __shared__ alignas(16) float sh_t[12][16];
  __shared__ float sh_y[21][17], sh_s3[21][17], sh_dy[42][17], sh_dv[12][17];
  __shared__ float sh_wg[2][6][16];
  __shared__ float sh_qd[6][16], sh_tau[6][16], sh_f[6][16];
  __shared__ float sh_c[6][16], sh_v[6][16];

  const int tid = threadIdx.x;
  const int l = tid & 63;
  const int w = tid >> 6;
  const int lane_n = l & 15;
  const int quad = l >> 4;
  const int base0 = w*16 + quad*4;
  const int base1 = (w+4)*16 + quad*4;
  const int s0 = blockIdx.x * 16;
  const int vm = viol[stage];

  const half8_t* fW2Lh  = (const half8_t*)(fragHi);
  const half8_t* fW2Ll  = (const half8_t*)(fragLo);
  const half8_t* fW2Vh  = (const half8_t*)(fragHi + 16384);
  const half8_t* fW2VTh = (const half8_t*)(fragHi + 32768);
  const half8_t* fW3h   = (const half8_t*)(fragHi + 49152);
  const half8_t* fW3l   = (const half8_t*)(fragLo + 49152);
  const half8_t* fW1Th  = (const half8_t*)(fragHi + 53248);

  // ---- phase 0: tile load, trig, tau, constraint force
  if (tid < 96){
    int s = tid & 15, i = tid >> 4;
    float q  = q_cur [(s0+s)*6 + i];
    float qd = qd_cur[(s0+s)*6 + i];
    sh_qd[i][s]=qd;
    sh_tau[i][s] = action[(s0+s)*6+i] * c_EFFORT[i];
    el(sh_t, 2*i,   s) = __cosf(q);
    el(sh_t, 2*i+1, s) = __sinf(q);
    float lo = c_LOWER[i]+0.1f, up = c_UPPER[i]-0.1f;
    float barrier = -5.0f*(1.0f/(q-lo) - 1.0f/(up-q));
    float clip = (q<=lo)? c_EFFORT[i] : ((q>=up)? -c_EFFORT[i] : 0.0f);
    sh_f[i][s] = ((vm>>i)&1) ? clip : barrier;
    sh_c[i][s] = 0.0f;
  }
  __syncthreads();

  float4 s1a, s1b;
  // ---- L1L (VALU) -> Bact (r11: plain fp16 activations, hi buffer only)
  {
    float2 bb = *reinterpret_cast<const float2*>(b1L + 2*l);
    float4 z0 = f4all(bb.x), z1 = f4all(bb.y);
    #pragma unroll
    for (int i=0;i<12;i++){
      float2 wv = *reinterpret_cast<const float2*>(W1LT + i*128 + 2*l);
      float4 a = *chunkc(sh_t, i, w);
      fma4(z0, wv.x, a); fma4(z1, wv.y, a);
    }
    float4 h0, h1;
    #pragma unroll
    for (int j=0;j<4;j++){
      spsig_f((&z0.x)[j], (&h0.x)[j], (&s1a.x)[j]);
      spsig_f((&z1.x)[j], (&h1.x)[j], (&s1b.x)[j]);
    }
    #pragma unroll
    for (int j=0;j<4;j++)
      stH2(Bact[0], 4*w+j, 2*l, (&h0.x)[j], (&h1.x)[j]);
  }
  __syncthreads();

  float4 s2a, s2b;
  // ---- L2L MFMA (mfma2: split weight x fp16 act) + epilogue in-place
  {
    f32x4 acc0 = {0.f,0.f,0.f,0.f}, acc1 = {0.f,0.f,0.f,0.f};
    #pragma unroll
    for (int q=0;q<4;q++){
      half8_t bh = ldB(Bact[0], lane_n, q, quad);
      acc0 = mfma2(fW2Lh[(w*4+q)*64+l],     fW2Ll[(w*4+q)*64+l],     bh, acc0);
      acc1 = mfma2(fW2Lh[((w+4)*4+q)*64+l], fW2Ll[((w+4)*4+q)*64+l], bh, acc1);
    }
    __syncthreads();
    float4 ba = *reinterpret_cast<const float4*>(b2L + base0);
    float4 bb = *reinterpret_cast<const float4*>(b2L + base1);
    float4 h2a, h2b;
    #pragma unroll
    for (int j=0;j<4;j++){
      spsig_f(acc0[j] + (&ba.x)[j], (&h2a.x)[j], (&s2a.x)[j]);
      spsig_f(acc1[j] + (&bb.x)[j], (&h2b.x)[j], (&s2b.x)[j]);
    }
    stH4(Bact[0], lane_n, base0, h2a);
    stH4(Bact[0], lane_n, base1, h2b);
  }
  __syncthreads();

  // ---- L3 MFMA (waves 0,1; mfma2) -> y, s3
  if (w < 2){
    f32x4 acc = {0.f,0.f,0.f,0.f};
    #pragma unroll
    for (int q=0;q<4;q++){
      half8_t bh = ldB(Bact[0], lane_n, q, quad);
      acc = mfma2(fW3h[(w*4+q)*64+l], fW3l[(w*4+q)*64+l], bh, acc);
    }
    int rb = w*16 + quad*4;
    #pragma unroll
    for (int j=0;j<4;j++){
      int r = rb + j;
      if (r < 21){
        float z = acc[j] + b3Lp[r];
        float sp, sg;
        spsig_f(z, sp, sg);
        sh_y[r][lane_n]  = sp;
        sh_s3[r][lane_n] = sg;
      }
    }
  }
  __syncthreads();
  // (Bact dead: sh_y/sh_s3 captured. Bd[0] free for tangents.)

  // ---- v = L^T qdot
  if (tid < 96){
    int s = tid & 15, jj = tid >> 4;
    float acc = 0.f;
    for (int i=jj;i<6;i++) acc = fmaf(sh_y[c_ROWOFF[i]+jj][s], sh_qd[i][s], acc);
    sh_v[jj][s] = acc;
  }

  // ---- tangent groups: dirs {2G, 2G+1} — plain fp16 path (r7)
  // r11: loop-end barrier removed (audit in round notes).
  for (int G=0; G<3; ++G){
    #pragma unroll
    for (int d=0; d<2; ++d){
      int g = 2*G + d;
      float2 w0 = *reinterpret_cast<const float2*>(W1LT + (2*g)*128 + 2*l);
      float2 w1 = *reinterpret_cast<const float2*>(W1LT + (2*g+1)*128 + 2*l);
      float4 tc = *chunkc(sh_t, 2*g,   w);
      float4 ts = *chunkc(sh_t, 2*g+1, w);
      #pragma unroll
      for (int j=0;j<4;j++){
        float tcj = (&tc.x)[j], tsj = (&ts.x)[j];
        float d0 = (&s1a.x)[j]*(tcj*w1.x - tsj*w0.x);
        float d1 = (&s1b.x)[j]*(tcj*w1.y - tsj*w0.y);
        stH2(Bd[d][0], 4*w+j, 2*l, d0, d1);
      }
    }
    __syncthreads();
    f32x4 ta00={0.f,0.f,0.f,0.f}, ta01=ta00, ta10=ta00, ta11=ta00;
    #pragma unroll
    for (int q=0;q<4;q++){
      half8_t b0h = ldB(Bd[0][0], lane_n, q, quad);
      half8_t b1h = ldB(Bd[1][0], lane_n, q, quad);
      half8_t a0h = fW2Lh[(w*4+q)*64+l];
      half8_t a1h = fW2Lh[((w+4)*4+q)*64+l];
      ta00 = mfma1(a0h, b0h, ta00);
      ta01 = mfma1(a0h, b1h, ta01);
      ta10 = mfma1(a1h, b0h, ta10);
      ta11 = mfma1(a1h, b1h, ta11);
    }
    __syncthreads();
    {
      float4 v;
      #pragma unroll
      for (int j=0;j<4;j++) (&v.x)[j] = (&s2a.x)[j]*ta00[j];
      stH4(Bd[0][0], lane_n, base0, v);
      #pragma unroll
      for (int j=0;j<4;j++) (&v.x)[j] = (&s2b.x)[j]*ta10[j];
      stH4(Bd[0][0], lane_n, base1, v);
      #pragma unroll
      for (int j=0;j<4;j++) (&v.x)[j] = (&s2a.x)[j]*ta01[j];
      stH4(Bd[1][0], lane_n, base0, v);
      #pragma unroll
      for (int j=0;j<4;j++) (&v.x)[j] = (&s2b.x)[j]*ta11[j];
      stH4(Bd[1][0], lane_n, base1, v);
    }
    __syncthreads();
    {
      int d = w & 1, tt = w >> 1;
      f32x4 acc = {0.f,0.f,0.f,0.f};
      #pragma unroll
      for (int q=0;q<4;q++){
        half8_t bh = ldB(Bd[d][0], lane_n, q, quad);
        acc = mfma1(fW3h[(tt*4+q)*64+l], bh, acc);
      }
      int rb = tt*16 + quad*4;
      #pragma unroll
      for (int j=0;j<4;j++){
        int r = rb + j;
        if (r < 21) sh_dy[d*21 + r][lane_n] = sh_s3[r][lane_n] * acc[j];
      }
    }
    __syncthreads();   // Bd reads drained; sh_dy ready
    if (tid < 32){
      int s = tid & 15, gg = tid >> 4;
      float qd[6];
      #pragma unroll
      for (int i=0;i<6;i++) qd[i] = sh_qd[i][s];
      float u[6];
      #pragma unroll
      for (int jj=0;jj<6;jj++){
        float acc = 0.f;
        for (int i=jj;i<6;i++) acc = fmaf(sh_dy[gg*21 + c_ROWOFF[i]+jj][s], qd[i], acc);
        u[jj] = acc;
      }
      #pragma unroll
      for (int i=0;i<6;i++){
        float acc = 0.f;
        for (int j=0;j<=i;j++){
          acc = fmaf(sh_dy[gg*21 + c_ROWOFF[i]+j][s], sh_v[j][s], acc);
          acc = fmaf(sh_y [c_ROWOFF[i]+j][s], u[j], acc);
        }
        sh_wg[gg][i][s] = acc;
      }
    }
    __syncthreads();
    if (tid < 96){
      int s = tid & 15, i = tid >> 4;
      float acc = sh_c[i][s];
      acc = fmaf(sh_qd[2*G][s],   sh_wg[0][i][s], acc);
      acc = fmaf(sh_qd[2*G+1][s], sh_wg[1][i][s], acc);
      int gi = i - 2*G;
      if (gi == 0 || gi == 1){
        float r = 0.f;
        #pragma unroll
        for (int j=0;j<6;j++) r = fmaf(sh_qd[j][s], sh_wg[gi][j][s], r);
        acc -= 0.5f*r;
      }
      sh_c[i][s] = acc;
    }
    // r11: NO barrier here. Next writes (stH2 into Bd / V-L1 into Bact) are
    // disjoint from sh_c/sh_wg; Bd readers drained at the dy-MFMA barrier;
    // next sh_wg write is >=2 barriers away (staging+MFMA barriers of G+1).
  }

  // ---- V-net L1 (VALU) -> Bact (plain fp16, hi buffer only)
  {
    float2 bb = *reinterpret_cast<const float2*>(b1V + 2*l);
    float4 z0 = f4all(bb.x), z1 = f4all(bb.y);
    #pragma unroll
    for (int i=0;i<12;i++){
      float2 wv = *reinterpret_cast<const float2*>(W1VT + i*128 + 2*l);
      float4 a = *chunkc(sh_t, i, w);
      fma4(z0, wv.x, a); fma4(z1, wv.y, a);
    }
    #pragma unroll
    for (int j=0;j<4;j++){
      float h0 = sp_f((&z0.x)[j]);
      float h1 = sp_f((&z1.x)[j]);
      stH2(Bact[0], 4*w+j, 2*l, h0, h1);
    }
  }
  __syncthreads();
  // ---- L2V MFMA (plain fp16); epilogue g2 = sig(z)*W3V -> Bact in-place
  {
    f32x4 acc0 = {0.f,0.f,0.f,0.f}, acc1 = {0.f,0.f,0.f,0.f};
    #pragma unroll
    for (int q=0;q<4;q++){
      half8_t bh = ldB(Bact[0], lane_n, q, quad);
      acc0 = mfma1(fW2Vh[(w*4+q)*64+l],     bh, acc0);
      acc1 = mfma1(fW2Vh[((w+4)*4+q)*64+l], bh, acc1);
    }
    __syncthreads();
    float4 ba  = *reinterpret_cast<const float4*>(b2V + base0);
    float4 bb  = *reinterpret_cast<const float4*>(b2V + base1);
    float4 w3a = *reinterpret_cast<const float4*>(W3V + base0);
    float4 w3b = *reinterpret_cast<const float4*>(W3V + base1);
    float4 g2a, g2b;
    #pragma unroll
    for (int j=0;j<4;j++){
      (&g2a.x)[j] = sig_f(acc0[j] + (&ba.x)[j]) * (&w3a.x)[j];
      (&g2b.x)[j] = sig_f(acc1[j] + (&bb.x)[j]) * (&w3b.x)[j];
    }
    stH4(Bact[0], lane_n, base0, g2a);
    stH4(Bact[0], lane_n, base1, g2b);
  }
  __syncthreads();
  // ---- V bwd MFMA (A = W2V^T, plain fp16); epilogue: s1V recompute, g1
  // ALIAS HAZARD: reads Bact[0] (g2), writes g1 to same buffer; barrier
  // below orders all reads before any write.
  {
    f32x4 acc0 = {0.f,0.f,0.f,0.f}, acc1 = {0.f,0.f,0.f,0.f};
    #pragma unroll
    for (int q=0;q<4;q++){
      half8_t bh = ldB(Bact[0], lane_n, q, quad);
      acc0 = mfma1(fW2VTh[(w*4+q)*64+l],     bh, acc0);
      acc1 = mfma1(fW2VTh[((w+4)*4+q)*64+l], bh, acc1);
    }
    float tn[12];
    #pragma unroll
    for (int i=0;i<12;i++) tn[i] = el(sh_t, i, lane_n);
    float4 g1a, g1b;
    #pragma unroll
    for (int j=0;j<4;j++){
      int r = base0 + j;
      float z = b1V[r];
      const float* wr = W1V + r*12;
      #pragma unroll
      for (int i=0;i<12;i++) z = fmaf(wr[i], tn[i], z);
      (&g1a.x)[j] = sig_f(z) * acc0[j];
      r = base1 + j;
      z = b1V[r];
      wr = W1V + r*12;
      #pragma unroll
      for (int i=0;i<12;i++) z = fmaf(wr[i], tn[i], z);
      (&g1b.x)[j] = sig_f(z) * acc1[j];
    }
    __syncthreads();   // all g2 reads complete before g1 overwrite (alias)
    stH4(Bact[0], lane_n, base0, g1a);
    stH4(Bact[0], lane_n, base1, g1b);
  }
  __syncthreads();
  // ---- dV/dt = W1V^T g1 via MFMA (wave 0 only; plain fp16)
  if (w == 0){
    f32x4 acc = {0.f,0.f,0.f,0.f};
    #pragma unroll
    for (int q=0;q<4;q++){
      half8_t bh = ldB(Bact[0], lane_n, q, quad);
      acc = mfma1(fW1Th[q*64+l], bh, acc);
    }
    int rb = quad*4;
    #pragma unroll
    for (int j=0;j<4;j++){
      int r = rb + j;
      if (r < 12) sh_dv[r][lane_n] = acc[j];
    }
  }
  __syncthreads();
  // ---- assembly + triangular solves + folded next-stage pre (+ final)
  // r11: gravity computed inline (sh_dv + sh_t), grav phase/barrier removed.
  if (l < 4){
    int s = w*4 + l;
    float Lm[21];
    #pragma unroll
    for (int o=0;o<21;o++) Lm[o] = sh_y[o][s];
    float rhs[6];
    #pragma unroll
    for (int i=0;i<6;i++){
      float grav = fmaf(el(sh_t,2*i,s), sh_dv[2*i+1][s],
                        -(el(sh_t,2*i+1,s)*sh_dv[2*i][s]));
      rhs[i] = sh_tau[i][s] - sh_c[i][s] - grav - sh_f[i][s];
    }
    float z[6];
    #pragma unroll
    for (int i=0;i<6;i++){
      float acc = rhs[i];
      for (int j=0;j<i;j++) acc = fmaf(-Lm[c_ROWOFF[i]+j], z[j], acc);
      z[i] = acc * __builtin_amdgcn_rcpf(Lm[c_ROWOFF[i]+i]);
    }
    float a[6];
    #pragma unroll
    for (int i=5;i>=0;i--){
      float acc = z[i];
      for (int j=i+1;j<6;j++) acc = fmaf(-Lm[c_ROWOFF[j]+i], a[j], acc);
      a[i] = acc * __builtin_amdgcn_rcpf(Lm[c_ROWOFF[i]+i]);
    }
    int b = s0 + s;
    float* kqd_out = kqd_all + stage*B6;
    #pragma unroll
    for (int i=0;i<6;i++) kqd_out[b*6+i] = a[i];

    if (stage < 3){
      const float* o = obs + b*12;
      unsigned mask = 0;
      #pragma unroll
      for (int i=0;i<6;i++){
        float q0=o[i], qd0=o[6+i];
        float q, qd;
        if (stage == 0){
          q  = q0 + 0.5f*DT*qd0;
          qd = qd0 + 0.5f*DT*a[i];
        } else if (stage == 1){
          float k1 = kqd_all[b*6+i];
          q  = q0 + 0.5f*DT*qd0 + 0.25f*DT*DT*k1;
          qd = qd0 + 0.5f*DT*a[i];
        } else {
          float k2 = kqd_all[B6 + b*6+i];
          q  = q0 + DT*qd0 + 0.5f*DT*DT*k2;
          qd = qd0 + DT*a[i];
        }
        q_cur[b*6+i]=q; qd_cur[b*6+i]=qd;
        float lo = c_LOWER[i]+0.1f, up = c_UPPER[i]-0.1f;
        if (q <= lo || q >= up) mask |= (1u<<i);
      }
      if (mask) atomicOr(viol + stage + 1, (int)mask);
    }

    if (fold_final){
      const float* o = obs + b*12;
      float* po = out + b*12;
      #pragma unroll
      for (int i=0;i<6;i++){
        float q0=o[i], qd0=o[6+i];
        float k1=kqd_all[b*6+i], k2=kqd_all[B6+b*6+i], k3=kqd_all[2*B6+b*6+i];
        float qn = q0 + DT*qd0 + (DT*DT/6.0f)*(k1+k2+k3);
        qn = fminf(fmaxf(qn, c_LOWER[i]), c_UPPER[i]);
        po[i] = qn;
        po[6+i] = qd0 + (DT/6.0f)*(k1 + 2.0f*k2 + 2.0f*k3 + a[i]);
      }
    }
  }
  #undef Bact
}

extern "C" void kernel_launch(void* const* d_in, const int* in_sizes, int n_in,
                              void* d_out, int out_size, void* d_ws, size_t ws_size,
                              hipStream_t stream) {
  const float* obs    = (const float*)d_in[0];
  const float* action = (const float*)d_in[1];
  const float* W1L = (const float*)d_in[2];  const float* b1L = (const float*)d_in[3];
  const float* W2L = (const float*)d_in[4];  const float* b2L = (const float*)d_in[5];
  const float* W3L = (const float*)d_in[6];  const float* b3L = (const float*)d_in[7];
  const float* W1V = (const float*)d_in[8];  const float* b1V = (const float*)d_in[9];
  const float* W2V = (const float*)d_in[10]; const float* b2V = (const float*)d_in[11];
  const float* W3V = (const float*)d_in[12]; // b3V unused: only grad of V needed

  float* ws = (float*)d_ws;
  _Float16* fragHi = (_Float16*)ws;            // 55296 halves
  _Float16* fragLo = fragHi + 55296;           // 55296 halves
  float* W1LT  = ws + 55296;                   // 1536
  float* W1VT  = W1LT + 1536;                  // 1536
  float* b3Lp  = W1VT + 1536;                  // 32
  float* q_cur  = b3Lp + 32;                   // B6
  float* qd_cur = q_cur + B6;                  // B6
  float* kqd    = qd_cur + B6;                 // 4*B6
  int*   viol   = (int*)(kqd + 4*B6);

  float* out = (float*)d_out;

  hipMemsetAsync(viol, 0, sizeof(int), stream);
  k_initpre<<<64,256,0,stream>>>(W1L, W2L, W3L, W1V, W2V, b3L, obs,
                                 W1LT, W1VT, b3Lp, fragHi, fragLo,
                                 q_cur, qd_cur, viol);
  for (int s=0; s<4; ++s){
    k_accel<<<1024,256,0,stream>>>(s, (s==3)?1:0, obs, q_cur, qd_cur, action,
        W1LT, b1L, b2L, b3Lp, W1VT, b1V, b2V, W3V, W1V,
        fragHi, fragLo, viol, kqd, out);
  }
}

// Round 12
// 219.148 us; speedup vs baseline: 1.1647x; 1.0462x over previous
//
#include <hip/hip_runtime.h>
#include <math.h>

#define BATCH 16384
#define B6 (BATCH*6)
#define DT 0.01f

using half8_t = __attribute__((ext_vector_type(8))) _Float16;
using half4_t = __attribute__((ext_vector_type(4))) _Float16;
using half2_t = __attribute__((ext_vector_type(2))) _Float16;
using f32x4   = __attribute__((ext_vector_type(4))) float;

__device__ __constant__ float c_LOWER[6]  = {-6.28f,-6.28f,-3.14f,-6.28f,-6.28f,-6.28f};
__device__ __constant__ float c_UPPER[6]  = { 6.28f, 6.28f, 3.14f, 6.28f, 6.28f, 6.28f};
__device__ __constant__ float c_EFFORT[6] = {150.0f,150.0f,150.0f,28.0f,28.0f,28.0f};
__device__ __constant__ int   c_ROWOFF[6] = {0,1,3,6,10,15};

__device__ __forceinline__ float sp_f(float z){
  return fmaxf(z,0.0f) + __logf(1.0f + __expf(-fabsf(z)));
}
__device__ __forceinline__ float sig_f(float z){
  return __builtin_amdgcn_rcpf(1.0f + __expf(-z));
}
// fused softplus+sigmoid sharing one exp (correctness-proven r6/r7)
__device__ __forceinline__ void spsig_f(float z, float& sp, float& sg){
  float e = __expf(-fabsf(z));
  float t = 1.0f + e;
  float r = __builtin_amdgcn_rcpf(t);
  sp = fmaxf(z,0.0f) + __logf(t);
  sg = (z >= 0.0f) ? r : e*r;
}

__device__ __forceinline__ float4 f4all(float v){ return make_float4(v,v,v,v); }
__device__ __forceinline__ void fma4(float4& acc, float w, float4 a){
  acc.x=fmaf(w,a.x,acc.x); acc.y=fmaf(w,a.y,acc.y); acc.z=fmaf(w,a.z,acc.z); acc.w=fmaf(w,a.w,acc.w);
}

// XOR-swizzled accessors for sh_t [12][16]
__device__ __forceinline__ const float4* chunkc(const float (*arr)[16], int n, int cc){
  return reinterpret_cast<const float4*>(&arr[n][4*(cc ^ ((n>>1)&3))]);
}
__device__ __forceinline__ float& el(float (*arr)[16], int n, int s){
  return arr[n][4*((s>>2) ^ ((n>>1)&3)) + (s&3)];
}

// ---- MFMA helpers --------------------------------------------------------
// mfma2: split WEIGHT (ah+al) x plain-fp16 activation bh.
__device__ __forceinline__ f32x4 mfma2(half8_t ah, half8_t al, half8_t bh, f32x4 acc){
  acc = __builtin_amdgcn_mfma_f32_16x16x32_f16(ah, bh, acc, 0,0,0);
  acc = __builtin_amdgcn_mfma_f32_16x16x32_f16(al, bh, acc, 0,0,0);
  return acc;
}
__device__ __forceinline__ f32x4 mfma1(half8_t ah, half8_t bh, f32x4 acc){
  return __builtin_amdgcn_mfma_f32_16x16x32_f16(ah, bh, acc, 0,0,0);
}
__device__ __forceinline__ half8_t ldB(const _Float16 (*B)[136], int n, int q, int quad){
  return *reinterpret_cast<const half8_t*>(&B[n][q*32 + quad*8]);
}
// plain-fp16 stores (tangent r7; V-net r10; L-path activations r11)
__device__ __forceinline__ void stH2(_Float16 (*Bh)[136], int n, int k2, float a, float b){
  half2_t hi; hi[0]=(_Float16)a; hi[1]=(_Float16)b;
  *reinterpret_cast<half2_t*>(&Bh[n][k2]) = hi;
}
__device__ __forceinline__ void stH4(_Float16 (*Bh)[136], int n, int base, float4 v){
  half4_t hi;
  #pragma unroll
  for (int j=0;j<4;j++) hi[j] = (_Float16)(&v.x)[j];
  *reinterpret_cast<half4_t*>(&Bh[n][base]) = hi;
}

// ---------------- merged init + stage-0 pre --------------------------------
// viol[0] zeroed by hipMemsetAsync before this kernel (capture-legal).
__global__ void __launch_bounds__(256) k_initpre(
    const float* __restrict__ W1L, const float* __restrict__ W2L,
    const float* __restrict__ W3L, const float* __restrict__ W1V,
    const float* __restrict__ W2V, const float* __restrict__ b3L,
    const float* __restrict__ obs,
    float* __restrict__ W1LT, float* __restrict__ W1VT, float* __restrict__ b3Lp,
    _Float16* __restrict__ fragHi, _Float16* __restrict__ fragLo,
    float* __restrict__ q_cur, float* __restrict__ qd_cur, int* __restrict__ viol)
{
  int t = blockIdx.x*256 + threadIdx.x;
  if (t >= 1 && t < 4) viol[t] = 0;
  if (t < 1536){ int i = t/128, k = t%128; W1LT[t] = W1L[k*12+i]; W1VT[t] = W1V[k*12+i]; }
  if (t < 32) b3Lp[t] = (t < 21) ? b3L[t] : 0.0f;
  if (t < 6912){
    int kind, f;
    if (t < 2048){ kind=0; f=t; }
    else if (t < 4096){ kind=1; f=t-2048; }
    else if (t < 6144){ kind=2; f=t-4096; }
    else if (t < 6656){ kind=3; f=t-6144; }
    else { kind=4; f=t-6656; }
    int tile = f>>8, q = (f>>6)&3, l = f&63, m = l&15, kq = 8*(l>>4);
    int off = (kind==0?0:kind==1?16384:kind==2?32768:kind==3?49152:53248) + f*8;
    #pragma unroll
    for (int e=0;e<8;e++){
      float v;
      int kk = 32*q + kq + e;
      if (kind==0)      v = W2L[(16*tile+m)*128 + kk];
      else if (kind==1) v = W2V[(16*tile+m)*128 + kk];
      else if (kind==2) v = W2V[kk*128 + (16*tile+m)];
      else if (kind==3){ int r = 16*tile+m; v = (r<21) ? W3L[r*128 + kk] : 0.0f; }
      else              v = (m<12) ? W1V[kk*12 + m] : 0.0f;
      _Float16 hi = (_Float16)v;
      _Float16 lo = (_Float16)(v - (float)hi);
      fragHi[off+e] = hi; fragLo[off+e] = lo;
    }
  }
  if (t < BATCH){
    const float* o = obs + t*12;
    unsigned mask = 0;
    #pragma unroll
    for (int i=0;i<6;i++){
      float q = o[i];
      q_cur[t*6+i]=q; qd_cur[t*6+i]=o[6+i];
      float lo = c_LOWER[i]+0.1f, up = c_UPPER[i]-0.1f;
      if (q <= lo || q >= up) mask |= (1u<<i);
    }
    unsigned wm = 0;
    #pragma unroll
    for (int i=0;i<6;i++) if (__ballot((int)((mask>>i)&1u))) wm |= (1u<<i);
    if ((threadIdx.x & 63)==0 && wm) atomicOr(viol, (int)wm);
  }
}

// ---------------- heavy per-stage accel (MFMA) -----------------------------
// 16 samples/block, 256 threads (4 waves), 1024 blocks.
// r12: s1V cached in LDS during V-L1 (spsig_f shares the exp) — kills the
// V-bwd epilogue recompute (2 b1V loads + 24 W1V loads + 96 FMA + 12 tn
// LDS reads per thread) at the cost of 8 ds_write + 8 ds_read. sh_s1V is
// [128][17] padded (+8.7KB LDS -> ~36.3KB, still 4 blocks/CU).
__global__ void __launch_bounds__(256) k_accel(
    int stage, int fold_final,
    const float* __restrict__ obs,
    float* __restrict__ q_cur, float* __restrict__ qd_cur,
    const float* __restrict__ action,
    const float* __restrict__ W1LT, const float* __restrict__ b1L,
    const float* __restrict__ b2L,  const float* __restrict__ b3Lp,
    const float* __restrict__ W1VT, const float* __restrict__ b1V,
    const float* __restrict__ b2V,  const float* __restrict__ W3V,
    const float* __restrict__ W1V,
    const _Float16* __restrict__ fragHi, const _Float16* __restrict__ fragLo,
    int* __restrict__ viol,
    float* __restrict__ kqd_all,
    float* __restrict__ out)
{
  // Bd[0] doubles as Bact (lifetime-disjoint; V-bwd alias covered by barrier)
  __shared__ alignas(16) _Float16 Bd[2][2][16][136];
  #define Bact Bd[0]
  __shared__ alignas(16) float sh_t[12][16];
  __shared__ float sh_y[21][17], sh_s3[21][17], sh_dy[42][17], sh_dv[12][17];
  __shared__ float sh_s1V[128][17];
  __shared__ float sh_wg[2][6][16];
  __shared__ float sh_qd[6][16], sh_tau[6][16], sh_f[6][16];
  __shared__ float sh_c[6][16], sh_v[6][16];

  const int tid = threadIdx.x;
  const int l = tid & 63;
  const int w = tid >> 6;
  const int lane_n = l & 15;
  const int quad = l >> 4;
  const int base0 = w*16 + quad*4;
  const int base1 = (w+4)*16 + quad*4;
  const int s0 = blockIdx.x * 16;
  const int vm = viol[stage];
  (void)W1V; // r12: no longer read in the accel body (s1V cached)

  const half8_t* fW2Lh  = (const half8_t*)(fragHi);
  const half8_t* fW2Ll  = (const half8_t*)(fragLo);
  const half8_t* fW2Vh  = (const half8_t*)(fragHi + 16384);
  const half8_t* fW2VTh = (const half8_t*)(fragHi + 32768);
  const half8_t* fW3h   = (const half8_t*)(fragHi + 49152);
  const half8_t* fW3l   = (const half8_t*)(fragLo + 49152);
  const half8_t* fW1Th  = (const half8_t*)(fragHi + 53248);

  // ---- phase 0: tile load, trig, tau, constraint force
  if (tid < 96){
    int s = tid & 15, i = tid >> 4;
    float q  = q_cur [(s0+s)*6 + i];
    float qd = qd_cur[(s0+s)*6 + i];
    sh_qd[i][s]=qd;
    sh_tau[i][s] = action[(s0+s)*6+i] * c_EFFORT[i];
    el(sh_t, 2*i,   s) = __cosf(q);
    el(sh_t, 2*i+1, s) = __sinf(q);
    float lo = c_LOWER[i]+0.1f, up = c_UPPER[i]-0.1f;
    float barrier = -5.0f*(1.0f/(q-lo) - 1.0f/(up-q));
    float clip = (q<=lo)? c_EFFORT[i] : ((q>=up)? -c_EFFORT[i] : 0.0f);
    sh_f[i][s] = ((vm>>i)&1) ? clip : barrier;
    sh_c[i][s] = 0.0f;
  }
  __syncthreads();

  float4 s1a, s1b;
  // ---- L1L (VALU) -> Bact (plain fp16 activations, hi buffer only)
  {
    float2 bb = *reinterpret_cast<const float2*>(b1L + 2*l);
    float4 z0 = f4all(bb.x), z1 = f4all(bb.y);
    #pragma unroll
    for (int i=0;i<12;i++){
      float2 wv = *reinterpret_cast<const float2*>(W1LT + i*128 + 2*l);
      float4 a = *chunkc(sh_t, i, w);
      fma4(z0, wv.x, a); fma4(z1, wv.y, a);
    }
    float4 h0, h1;
    #pragma unroll
    for (int j=0;j<4;j++){
      spsig_f((&z0.x)[j], (&h0.x)[j], (&s1a.x)[j]);
      spsig_f((&z1.x)[j], (&h1.x)[j], (&s1b.x)[j]);
    }
    #pragma unroll
    for (int j=0;j<4;j++)
      stH2(Bact[0], 4*w+j, 2*l, (&h0.x)[j], (&h1.x)[j]);
  }
  __syncthreads();

  float4 s2a, s2b;
  // ---- L2L MFMA (mfma2: split weight x fp16 act) + epilogue in-place
  {
    f32x4 acc0 = {0.f,0.f,0.f,0.f}, acc1 = {0.f,0.f,0.f,0.f};
    #pragma unroll
    for (int q=0;q<4;q++){
      half8_t bh = ldB(Bact[0], lane_n, q, quad);
      acc0 = mfma2(fW2Lh[(w*4+q)*64+l],     fW2Ll[(w*4+q)*64+l],     bh, acc0);
      acc1 = mfma2(fW2Lh[((w+4)*4+q)*64+l], fW2Ll[((w+4)*4+q)*64+l], bh, acc1);
    }
    __syncthreads();
    float4 ba = *reinterpret_cast<const float4*>(b2L + base0);
    float4 bb = *reinterpret_cast<const float4*>(b2L + base1);
    float4 h2a, h2b;
    #pragma unroll
    for (int j=0;j<4;j++){
      spsig_f(acc0[j] + (&ba.x)[j], (&h2a.x)[j], (&s2a.x)[j]);
      spsig_f(acc1[j] + (&bb.x)[j], (&h2b.x)[j], (&s2b.x)[j]);
    }
    stH4(Bact[0], lane_n, base0, h2a);
    stH4(Bact[0], lane_n, base1, h2b);
  }
  __syncthreads();

  // ---- L3 MFMA (waves 0,1; mfma2) -> y, s3
  if (w < 2){
    f32x4 acc = {0.f,0.f,0.f,0.f};
    #pragma unroll
    for (int q=0;q<4;q++){
      half8_t bh = ldB(Bact[0], lane_n, q, quad);
      acc = mfma2(fW3h[(w*4+q)*64+l], fW3l[(w*4+q)*64+l], bh, acc);
    }
    int rb = w*16 + quad*4;
    #pragma unroll
    for (int j=0;j<4;j++){
      int r = rb + j;
      if (r < 21){
        float z = acc[j] + b3Lp[r];
        float sp, sg;
        spsig_f(z, sp, sg);
        sh_y[r][lane_n]  = sp;
        sh_s3[r][lane_n] = sg;
      }
    }
  }
  __syncthreads();
  // (Bact dead: sh_y/sh_s3 captured. Bd[0] free for tangents.)

  // ---- v = L^T qdot
  if (tid < 96){
    int s = tid & 15, jj = tid >> 4;
    float acc = 0.f;
    for (int i=jj;i<6;i++) acc = fmaf(sh_y[c_ROWOFF[i]+jj][s], sh_qd[i][s], acc);
    sh_v[jj][s] = acc;
  }

  // ---- tangent groups: dirs {2G, 2G+1} — plain fp16 path
  for (int G=0; G<3; ++G){
    #pragma unroll
    for (int d=0; d<2; ++d){
      int g = 2*G + d;
      float2 w0 = *reinterpret_cast<const float2*>(W1LT + (2*g)*128 + 2*l);
      float2 w1 = *reinterpret_cast<const float2*>(W1LT + (2*g+1)*128 + 2*l);
      float4 tc = *chunkc(sh_t, 2*g,   w);
      float4 ts = *chunkc(sh_t, 2*g+1, w);
      #pragma unroll
      for (int j=0;j<4;j++){
        float tcj = (&tc.x)[j], tsj = (&ts.x)[j];
        float d0 = (&s1a.x)[j]*(tcj*w1.x - tsj*w0.x);
        float d1 = (&s1b.x)[j]*(tcj*w1.y - tsj*w0.y);
        stH2(Bd[d][0], 4*w+j, 2*l, d0, d1);
      }
    }
    __syncthreads();
    f32x4 ta00={0.f,0.f,0.f,0.f}, ta01=ta00, ta10=ta00, ta11=ta00;
    #pragma unroll
    for (int q=0;q<4;q++){
      half8_t b0h = ldB(Bd[0][0], lane_n, q, quad);
      half8_t b1h = ldB(Bd[1][0], lane_n, q, quad);
      half8_t a0h = fW2Lh[(w*4+q)*64+l];
      half8_t a1h = fW2Lh[((w+4)*4+q)*64+l];
      ta00 = mfma1(a0h, b0h, ta00);
      ta01 = mfma1(a0h, b1h, ta01);
      ta10 = mfma1(a1h, b0h, ta10);
      ta11 = mfma1(a1h, b1h, ta11);
    }
    __syncthreads();
    {
      float4 v;
      #pragma unroll
      for (int j=0;j<4;j++) (&v.x)[j] = (&s2a.x)[j]*ta00[j];
      stH4(Bd[0][0], lane_n, base0, v);
      #pragma unroll
      for (int j=0;j<4;j++) (&v.x)[j] = (&s2b.x)[j]*ta10[j];
      stH4(Bd[0][0], lane_n, base1, v);
      #pragma unroll
      for (int j=0;j<4;j++) (&v.x)[j] = (&s2a.x)[j]*ta01[j];
      stH4(Bd[1][0], lane_n, base0, v);
      #pragma unroll
      for (int j=0;j<4;j++) (&v.x)[j] = (&s2b.x)[j]*ta11[j];
      stH4(Bd[1][0], lane_n, base1, v);
    }
    __syncthreads();
    {
      int d = w & 1, tt = w >> 1;
      f32x4 acc = {0.f,0.f,0.f,0.f};
      #pragma unroll
      for (int q=0;q<4;q++){
        half8_t bh = ldB(Bd[d][0], lane_n, q, quad);
        acc = mfma1(fW3h[(tt*4+q)*64+l], bh, acc);
      }
      int rb = tt*16 + quad*4;
      #pragma unroll
      for (int j=0;j<4;j++){
        int r = rb + j;
        if (r < 21) sh_dy[d*21 + r][lane_n] = sh_s3[r][lane_n] * acc[j];
      }
    }
    __syncthreads();   // Bd reads drained; sh_dy ready
    if (tid < 32){
      int s = tid & 15, gg = tid >> 4;
      float qd[6];
      #pragma unroll
      for (int i=0;i<6;i++) qd[i] = sh_qd[i][s];
      float u[6];
      #pragma unroll
      for (int jj=0;jj<6;jj++){
        float acc = 0.f;
        for (int i=jj;i<6;i++) acc = fmaf(sh_dy[gg*21 + c_ROWOFF[i]+jj][s], qd[i], acc);
        u[jj] = acc;
      }
      #pragma unroll
      for (int i=0;i<6;i++){
        float acc = 0.f;
        for (int j=0;j<=i;j++){
          acc = fmaf(sh_dy[gg*21 + c_ROWOFF[i]+j][s], sh_v[j][s], acc);
          acc = fmaf(sh_y [c_ROWOFF[i]+j][s], u[j], acc);
        }
        sh_wg[gg][i][s] = acc;
      }
    }
    __syncthreads();
    if (tid < 96){
      int s = tid & 15, i = tid >> 4;
      float acc = sh_c[i][s];
      acc = fmaf(sh_qd[2*G][s],   sh_wg[0][i][s], acc);
      acc = fmaf(sh_qd[2*G+1][s], sh_wg[1][i][s], acc);
      int gi = i - 2*G;
      if (gi == 0 || gi == 1){
        float r = 0.f;
        #pragma unroll
        for (int j=0;j<6;j++) r = fmaf(sh_qd[j][s], sh_wg[gi][j][s], r);
        acc -= 0.5f*r;
      }
      sh_c[i][s] = acc;
    }
    // NO barrier here (r11 audit): next writes disjoint; Bd readers drained;
    // next sh_wg write is >=2 barriers away.
  }

  // ---- V-net L1 (VALU) -> Bact + s1V LDS cache (r12)
  {
    float2 bb = *reinterpret_cast<const float2*>(b1V + 2*l);
    float4 z0 = f4all(bb.x), z1 = f4all(bb.y);
    #pragma unroll
    for (int i=0;i<12;i++){
      float2 wv = *reinterpret_cast<const float2*>(W1VT + i*128 + 2*l);
      float4 a = *chunkc(sh_t, i, w);
      fma4(z0, wv.x, a); fma4(z1, wv.y, a);
    }
    #pragma unroll
    for (int j=0;j<4;j++){
      float h0, h1, g0, g1;
      spsig_f((&z0.x)[j], h0, g0);
      spsig_f((&z1.x)[j], h1, g1);
      stH2(Bact[0], 4*w+j, 2*l, h0, h1);
      sh_s1V[2*l  ][4*w+j] = g0;
      sh_s1V[2*l+1][4*w+j] = g1;
    }
  }
  __syncthreads();
  // ---- L2V MFMA (plain fp16); epilogue g2 = sig(z)*W3V -> Bact in-place
  {
    f32x4 acc0 = {0.f,0.f,0.f,0.f}, acc1 = {0.f,0.f,0.f,0.f};
    #pragma unroll
    for (int q=0;q<4;q++){
      half8_t bh = ldB(Bact[0], lane_n, q, quad);
      acc0 = mfma1(fW2Vh[(w*4+q)*64+l],     bh, acc0);
      acc1 = mfma1(fW2Vh[((w+4)*4+q)*64+l], bh, acc1);
    }
    __syncthreads();
    float4 ba  = *reinterpret_cast<const float4*>(b2V + base0);
    float4 bb  = *reinterpret_cast<const float4*>(b2V + base1);
    float4 w3a = *reinterpret_cast<const float4*>(W3V + base0);
    float4 w3b = *reinterpret_cast<const float4*>(W3V + base1);
    float4 g2a, g2b;
    #pragma unroll
    for (int j=0;j<4;j++){
      (&g2a.x)[j] = sig_f(acc0[j] + (&ba.x)[j]) * (&w3a.x)[j];
      (&g2b.x)[j] = sig_f(acc1[j] + (&bb.x)[j]) * (&w3b.x)[j];
    }
    stH4(Bact[0], lane_n, base0, g2a);
    stH4(Bact[0], lane_n, base1, g2b);
  }
  __syncthreads();
  // ---- V bwd MFMA (A = W2V^T, plain fp16); epilogue: g1 = s1V * acc
  // (s1V from LDS cache — recompute eliminated, r12)
  // ALIAS HAZARD: reads Bact[0] (g2), writes g1 to same buffer; barrier
  // below orders all reads before any write.
  {
    f32x4 acc0 = {0.f,0.f,0.f,0.f}, acc1 = {0.f,0.f,0.f,0.f};
    #pragma unroll
    for (int q=0;q<4;q++){
      half8_t bh = ldB(Bact[0], lane_n, q, quad);
      acc0 = mfma1(fW2VTh[(w*4+q)*64+l],     bh, acc0);
      acc1 = mfma1(fW2VTh[((w+4)*4+q)*64+l], bh, acc1);
    }
    float4 g1a, g1b;
    #pragma unroll
    for (int j=0;j<4;j++){
      (&g1a.x)[j] = sh_s1V[base0+j][lane_n] * acc0[j];
      (&g1b.x)[j] = sh_s1V[base1+j][lane_n] * acc1[j];
    }
    __syncthreads();   // all g2 reads complete before g1 overwrite (alias)
    stH4(Bact[0], lane_n, base0, g1a);
    stH4(Bact[0], lane_n, base1, g1b);
  }
  __syncthreads();
  // ---- dV/dt = W1V^T g1 via MFMA (wave 0 only; plain fp16)
  if (w == 0){
    f32x4 acc = {0.f,0.f,0.f,0.f};
    #pragma unroll
    for (int q=0;q<4;q++){
      half8_t bh = ldB(Bact[0], lane_n, q, quad);
      acc = mfma1(fW1Th[q*64+l], bh, acc);
    }
    int rb = quad*4;
    #pragma unroll
    for (int j=0;j<4;j++){
      int r = rb + j;
      if (r < 12) sh_dv[r][lane_n] = acc[j];
    }
  }
  __syncthreads();
  // ---- assembly + triangular solves + folded next-stage pre (+ final)
  // gravity inline (r11).
  if (l < 4){
    int s = w*4 + l;
    float Lm[21];
    #pragma unroll
    for (int o=0;o<21;o++) Lm[o] = sh_y[o][s];
    float rhs[6];
    #pragma unroll
    for (int i=0;i<6;i++){
      float grav = fmaf(el(sh_t,2*i,s), sh_dv[2*i+1][s],
                        -(el(sh_t,2*i+1,s)*sh_dv[2*i][s]));
      rhs[i] = sh_tau[i][s] - sh_c[i][s] - grav - sh_f[i][s];
    }
    float z[6];
    #pragma unroll
    for (int i=0;i<6;i++){
      float acc = rhs[i];
      for (int j=0;j<i;j++) acc = fmaf(-Lm[c_ROWOFF[i]+j], z[j], acc);
      z[i] = acc * __builtin_amdgcn_rcpf(Lm[c_ROWOFF[i]+i]);
    }
    float a[6];
    #pragma unroll
    for (int i=5;i>=0;i--){
      float acc = z[i];
      for (int j=i+1;j<6;j++) acc = fmaf(-Lm[c_ROWOFF[j]+i], a[j], acc);
      a[i] = acc * __builtin_amdgcn_rcpf(Lm[c_ROWOFF[i]+i]);
    }
    int b = s0 + s;
    float* kqd_out = kqd_all + stage*B6;
    #pragma unroll
    for (int i=0;i<6;i++) kqd_out[b*6+i] = a[i];

    if (stage < 3){
      const float* o = obs + b*12;
      unsigned mask = 0;
      #pragma unroll
      for (int i=0;i<6;i++){
        float q0=o[i], qd0=o[6+i];
        float q, qd;
        if (stage == 0){
          q  = q0 + 0.5f*DT*qd0;
          qd = qd0 + 0.5f*DT*a[i];
        } else if (stage == 1){
          float k1 = kqd_all[b*6+i];
          q  = q0 + 0.5f*DT*qd0 + 0.25f*DT*DT*k1;
          qd = qd0 + 0.5f*DT*a[i];
        } else {
          float k2 = kqd_all[B6 + b*6+i];
          q  = q0 + DT*qd0 + 0.5f*DT*DT*k2;
          qd = qd0 + DT*a[i];
        }
        q_cur[b*6+i]=q; qd_cur[b*6+i]=qd;
        float lo = c_LOWER[i]+0.1f, up = c_UPPER[i]-0.1f;
        if (q <= lo || q >= up) mask |= (1u<<i);
      }
      if (mask) atomicOr(viol + stage + 1, (int)mask);
    }

    if (fold_final){
      const float* o = obs + b*12;
      float* po = out + b*12;
      #pragma unroll
      for (int i=0;i<6;i++){
        float q0=o[i], qd0=o[6+i];
        float k1=kqd_all[b*6+i], k2=kqd_all[B6+b*6+i], k3=kqd_all[2*B6+b*6+i];
        float qn = q0 + DT*qd0 + (DT*DT/6.0f)*(k1+k2+k3);
        qn = fminf(fmaxf(qn, c_LOWER[i]), c_UPPER[i]);
        po[i] = qn;
        po[6+i] = qd0 + (DT/6.0f)*(k1 + 2.0f*k2 + 2.0f*k3 + a[i]);
      }
    }
  }
  #undef Bact
}

extern "C" void kernel_launch(void* const* d_in, const int* in_sizes, int n_in,
                              void* d_out, int out_size, void* d_ws, size_t ws_size,
                              hipStream_t stream) {
  const float* obs    = (const float*)d_in[0];
  const float* action = (const float*)d_in[1];
  const float* W1L = (const float*)d_in[2];  const float* b1L = (const float*)d_in[3];
  const float* W2L = (const float*)d_in[4];  const float* b2L = (const float*)d_in[5];
  const float* W3L = (const float*)d_in[6];  const float* b3L = (const float*)d_in[7];
  const float* W1V = (const float*)d_in[8];  const float* b1V = (const float*)d_in[9];
  const float* W2V = (const float*)d_in[10]; const float* b2V = (const float*)d_in[11];
  const float* W3V = (const float*)d_in[12]; // b3V unused: only grad of V needed

  float* ws = (float*)d_ws;
  _Float16* fragHi = (_Float16*)ws;            // 55296 halves
  _Float16* fragLo = fragHi + 55296;           // 55296 halves
  float* W1LT  = ws + 55296;                   // 1536
  float* W1VT  = W1LT + 1536;                  // 1536
  float* b3Lp  = W1VT + 1536;                  // 32
  float* q_cur  = b3Lp + 32;                   // B6
  float* qd_cur = q_cur + B6;                  // B6
  float* kqd    = qd_cur + B6;                 // 4*B6
  int*   viol   = (int*)(kqd + 4*B6);

  float* out = (float*)d_out;

  hipMemsetAsync(viol, 0, sizeof(int), stream);
  k_initpre<<<64,256,0,stream>>>(W1L, W2L, W3L, W1V, W2V, b3L, obs,
                                 W1LT, W1VT, b3Lp, fragHi, fragLo,
                                 q_cur, qd_cur, viol);
  for (int s=0; s<4; ++s){
    k_accel<<<1024,256,0,stream>>>(s, (s==3)?1:0, obs, q_cur, qd_cur, action,
        W1LT, b1L, b2L, b3Lp, W1VT, b1V, b2V, W3V, W1V,
        fragHi, fragLo, viol, kqd, out);
  }
}

// Round 13
// 178.149 us; speedup vs baseline: 1.4328x; 1.2301x over previous
//
#include <hip/hip_runtime.h>
#include <math.h>

#define BATCH 16384
#define B6 (BATCH*6)
#define DT 0.01f

using half8_t = __attribute__((ext_vector_type(8))) _Float16;
using half4_t = __attribute__((ext_vector_type(4))) _Float16;
using half2_t = __attribute__((ext_vector_type(2))) _Float16;
using f32x4   = __attribute__((ext_vector_type(4))) float;

__device__ __constant__ float c_LOWER[6]  = {-6.28f,-6.28f,-3.14f,-6.28f,-6.28f,-6.28f};
__device__ __constant__ float c_UPPER[6]  = { 6.28f, 6.28f, 3.14f, 6.28f, 6.28f, 6.28f};
__device__ __constant__ float c_EFFORT[6] = {150.0f,150.0f,150.0f,28.0f,28.0f,28.0f};
__device__ __constant__ int   c_ROWOFF[6] = {0,1,3,6,10,15};

__device__ __forceinline__ float sp_f(float z){
  return fmaxf(z,0.0f) + __logf(1.0f + __expf(-fabsf(z)));
}
__device__ __forceinline__ float sig_f(float z){
  return __builtin_amdgcn_rcpf(1.0f + __expf(-z));
}
// fused softplus+sigmoid sharing one exp (correctness-proven r6/r7)
__device__ __forceinline__ void spsig_f(float z, float& sp, float& sg){
  float e = __expf(-fabsf(z));
  float t = 1.0f + e;
  float r = __builtin_amdgcn_rcpf(t);
  sp = fmaxf(z,0.0f) + __logf(t);
  sg = (z >= 0.0f) ? r : e*r;
}

__device__ __forceinline__ float4 f4all(float v){ return make_float4(v,v,v,v); }
__device__ __forceinline__ void fma4(float4& acc, float w, float4 a){
  acc.x=fmaf(w,a.x,acc.x); acc.y=fmaf(w,a.y,acc.y); acc.z=fmaf(w,a.z,acc.z); acc.w=fmaf(w,a.w,acc.w);
}

// XOR-swizzled accessors for sh_t [12][16]
__device__ __forceinline__ const float4* chunkc(const float (*arr)[16], int n, int cc){
  return reinterpret_cast<const float4*>(&arr[n][4*(cc ^ ((n>>1)&3))]);
}
__device__ __forceinline__ float& el(float (*arr)[16], int n, int s){
  return arr[n][4*((s>>2) ^ ((n>>1)&3)) + (s&3)];
}

// ---- MFMA helpers --------------------------------------------------------
// mfma2: split WEIGHT (ah+al) x plain-fp16 activation bh.
__device__ __forceinline__ f32x4 mfma2(half8_t ah, half8_t al, half8_t bh, f32x4 acc){
  acc = __builtin_amdgcn_mfma_f32_16x16x32_f16(ah, bh, acc, 0,0,0);
  acc = __builtin_amdgcn_mfma_f32_16x16x32_f16(al, bh, acc, 0,0,0);
  return acc;
}
__device__ __forceinline__ f32x4 mfma1(half8_t ah, half8_t bh, f32x4 acc){
  return __builtin_amdgcn_mfma_f32_16x16x32_f16(ah, bh, acc, 0,0,0);
}
__device__ __forceinline__ half8_t ldB(const _Float16 (*B)[136], int n, int q, int quad){
  return *reinterpret_cast<const half8_t*>(&B[n][q*32 + quad*8]);
}
// plain-fp16 stores (tangent r7; V-net r10; L-path activations r11)
__device__ __forceinline__ void stH2(_Float16 (*Bh)[136], int n, int k2, float a, float b){
  half2_t hi; hi[0]=(_Float16)a; hi[1]=(_Float16)b;
  *reinterpret_cast<half2_t*>(&Bh[n][k2]) = hi;
}
__device__ __forceinline__ void stH4(_Float16 (*Bh)[136], int n, int base, float4 v){
  half4_t hi;
  #pragma unroll
  for (int j=0;j<4;j++) hi[j] = (_Float16)(&v.x)[j];
  *reinterpret_cast<half4_t*>(&Bh[n][base]) = hi;
}

// ---------------- merged init + stage-0 pre --------------------------------
// r13 frag regions (halves): W2L@0, W2V@16384, W2V^T@32768, W3L@49152,
// W1V^T-old@53248, W1L-A(K=32,pad12)@57344, W1V-A@61440. Total 65536/buffer.
// viol[0] zeroed by hipMemsetAsync before this kernel (capture-legal).
__global__ void __launch_bounds__(256) k_initpre(
    const float* __restrict__ W1L, const float* __restrict__ W2L,
    const float* __restrict__ W3L, const float* __restrict__ W1V,
    const float* __restrict__ W2V, const float* __restrict__ b3L,
    const float* __restrict__ obs,
    float* __restrict__ W1LT, float* __restrict__ W1VT, float* __restrict__ b3Lp,
    _Float16* __restrict__ fragHi, _Float16* __restrict__ fragLo,
    float* __restrict__ q_cur, float* __restrict__ qd_cur, int* __restrict__ viol)
{
  int t = blockIdx.x*256 + threadIdx.x;
  if (t >= 1 && t < 4) viol[t] = 0;
  if (t < 1536){ int i = t/128, k = t%128; W1LT[t] = W1L[k*12+i]; W1VT[t] = W1V[k*12+i]; }
  if (t < 32) b3Lp[t] = (t < 21) ? b3L[t] : 0.0f;
  if (t < 7936){
    int kind, f;
    if (t < 2048){ kind=0; f=t; }
    else if (t < 4096){ kind=1; f=t-2048; }
    else if (t < 6144){ kind=2; f=t-4096; }
    else if (t < 6656){ kind=3; f=t-6144; }
    else if (t < 6912){ kind=4; f=t-6656; }
    else if (t < 7424){ kind=5; f=t-6912; }   // W1L-A: 8 tiles x 64 lanes
    else { kind=6; f=t-7424; }                // W1V-A: 8 tiles x 64 lanes
    int tile, l, m, kq, off;
    if (kind < 5){
      tile = f>>8; int q = (f>>6)&3; l = f&63; m = l&15; kq = 32*q + 8*(l>>4);
      off = (kind==0?0:kind==1?16384:kind==2?32768:kind==3?49152:53248) + f*8;
    } else {
      tile = f>>6; l = f&63; m = l&15; kq = 8*(l>>4);
      off = (kind==5?57344:61440) + f*8;
    }
    #pragma unroll
    for (int e=0;e<8;e++){
      float v;
      int kk = kq + e;
      if (kind==0)      v = W2L[(16*tile+m)*128 + kk];
      else if (kind==1) v = W2V[(16*tile+m)*128 + kk];
      else if (kind==2) v = W2V[kk*128 + (16*tile+m)];
      else if (kind==3){ int r = 16*tile+m; v = (r<21) ? W3L[r*128 + kk] : 0.0f; }
      else if (kind==4) v = (m<12) ? W1V[kk*12 + m] : 0.0f;
      else if (kind==5) v = (kk<12) ? W1L[(16*tile+m)*12 + kk] : 0.0f;
      else              v = (kk<12) ? W1V[(16*tile+m)*12 + kk] : 0.0f;
      _Float16 hi = (_Float16)v;
      _Float16 lo = (_Float16)(v - (float)hi);
      fragHi[off+e] = hi; fragLo[off+e] = lo;
    }
  }
  if (t < BATCH){
    const float* o = obs + t*12;
    unsigned mask = 0;
    #pragma unroll
    for (int i=0;i<6;i++){
      float q = o[i];
      q_cur[t*6+i]=q; qd_cur[t*6+i]=o[6+i];
      float lo = c_LOWER[i]+0.1f, up = c_UPPER[i]-0.1f;
      if (q <= lo || q >= up) mask |= (1u<<i);
    }
    unsigned wm = 0;
    #pragma unroll
    for (int i=0;i<6;i++) if (__ballot((int)((mask>>i)&1u))) wm |= (1u<<i);
    if ((threadIdx.x & 63)==0 && wm) atomicOr(viol, (int)wm);
  }
}

// ---------------- heavy per-stage accel (MFMA) -----------------------------
// 16 samples/block, 256 threads (4 waves), 1024 blocks.
// r13: L1 layers moved to MFMA (K=32, pad 12). tB = fp16 trig staged in
// phase 0 ([16][40]: 80B row stride keeps ds_read_b128 16B-aligned, 2-way
// banks = free). MFMA C layout (col=sample, row=quad*4+j) == L2L epilogue
// mapping -> h stores identical stH4 pattern; V-L1 sigmoid stays in REGS
// (same thread as V-bwd consumer; r12's sh_s1V deleted); L-path s1 routed
// via sh_s1L aliased onto Bd[1] (written L1L, reg-loaded right after L1L
// barrier, before staging writes Bd[1] — cross-wave safety: staging is
// after the L3 barrier, which is after every wave's s1L reads+L2L barrier).
__global__ void __launch_bounds__(256) k_accel(
    int stage, int fold_final,
    const float* __restrict__ obs,
    float* __restrict__ q_cur, float* __restrict__ qd_cur,
    const float* __restrict__ action,
    const float* __restrict__ W1LT, const float* __restrict__ b1L,
    const float* __restrict__ b2L,  const float* __restrict__ b3Lp,
    const float* __restrict__ W1VT, const float* __restrict__ b1V,
    const float* __restrict__ b2V,  const float* __restrict__ W3V,
    const float* __restrict__ W1V,
    const _Float16* __restrict__ fragHi, const _Float16* __restrict__ fragLo,
    int* __restrict__ viol,
    float* __restrict__ kqd_all,
    float* __restrict__ out)
{
  // Bd[0] doubles as Bact; Bd[1] doubles as sh_s1L (fp32 [128][17], 8704B
  // exact fit) during the L1L->reg-load window (lifetime-disjoint).
  __shared__ alignas(16) _Float16 Bd[2][2][16][136];
  #define Bact Bd[0]
  __shared__ alignas(16) _Float16 tB[16][40];
  __shared__ alignas(16) float sh_t[12][16];
  __shared__ float sh_y[21][17], sh_s3[21][17], sh_dy[42][17], sh_dv[12][17];
  __shared__ float sh_wg[2][6][16];
  __shared__ float sh_qd[6][16], sh_tau[6][16], sh_f[6][16];
  __shared__ float sh_c[6][16], sh_v[6][16];

  float (*sh_s1L)[17] = reinterpret_cast<float(*)[17]>(&Bd[1][0][0][0]);

  const int tid = threadIdx.x;
  const int l = tid & 63;
  const int w = tid >> 6;
  const int lane_n = l & 15;
  const int quad = l >> 4;
  const int base0 = w*16 + quad*4;
  const int base1 = (w+4)*16 + quad*4;
  const int s0 = blockIdx.x * 16;
  const int vm = viol[stage];
  (void)W1V; (void)W1VT; // r13: L1 layers fully on MFMA fragments

  const half8_t* fW2Lh  = (const half8_t*)(fragHi);
  const half8_t* fW2Ll  = (const half8_t*)(fragLo);
  const half8_t* fW2Vh  = (const half8_t*)(fragHi + 16384);
  const half8_t* fW2VTh = (const half8_t*)(fragHi + 32768);
  const half8_t* fW3h   = (const half8_t*)(fragHi + 49152);
  const half8_t* fW3l   = (const half8_t*)(fragLo + 49152);
  const half8_t* fW1Th  = (const half8_t*)(fragHi + 53248);
  const half8_t* fW1LAh = (const half8_t*)(fragHi + 57344);
  const half8_t* fW1LAl = (const half8_t*)(fragLo + 57344);
  const half8_t* fW1VAh = (const half8_t*)(fragHi + 61440);

  // ---- phase 0: tile load, trig (fp32 sh_t + fp16 tB), tau, constraints
  if (tid < 96){
    int s = tid & 15, i = tid >> 4;
    float q  = q_cur [(s0+s)*6 + i];
    float qd = qd_cur[(s0+s)*6 + i];
    sh_qd[i][s]=qd;
    sh_tau[i][s] = action[(s0+s)*6+i] * c_EFFORT[i];
    float cq = __cosf(q), sq = __sinf(q);
    el(sh_t, 2*i,   s) = cq;
    el(sh_t, 2*i+1, s) = sq;
    tB[s][2*i]   = (_Float16)cq;
    tB[s][2*i+1] = (_Float16)sq;
    float lo = c_LOWER[i]+0.1f, up = c_UPPER[i]-0.1f;
    float barrier = -5.0f*(1.0f/(q-lo) - 1.0f/(up-q));
    float clip = (q<=lo)? c_EFFORT[i] : ((q>=up)? -c_EFFORT[i] : 0.0f);
    sh_f[i][s] = ((vm>>i)&1) ? clip : barrier;
    sh_c[i][s] = 0.0f;
  } else {
    // zero-pad tB K cols 12..31 (16 samples x 20 cols = 320, 160 thr x 2)
    int t2 = tid - 96;
    #pragma unroll
    for (int r=0;r<2;r++){
      int idx = 2*t2 + r;
      if (idx < 320){ int s = idx/20, c = 12 + idx%20; tB[s][c] = (_Float16)0.0f; }
    }
  }
  __syncthreads();

  // B fragment of tB for both L1 MFMAs (row=sample l&15, K=quad*8..+7)
  const half8_t tBfrag = *reinterpret_cast<const half8_t*>(&tB[lane_n][quad*8]);

  // ---- L1L via MFMA (split weight x fp16 trig) -> Bact + s1L to LDS
  {
    f32x4 acc0 = {0.f,0.f,0.f,0.f}, acc1 = {0.f,0.f,0.f,0.f};
    acc0 = mfma2(fW1LAh[w*64+l],     fW1LAl[w*64+l],     tBfrag, acc0);
    acc1 = mfma2(fW1LAh[(w+4)*64+l], fW1LAl[(w+4)*64+l], tBfrag, acc1);
    float4 ba = *reinterpret_cast<const float4*>(b1L + base0);
    float4 bb = *reinterpret_cast<const float4*>(b1L + base1);
    float4 h0, h1;
    #pragma unroll
    for (int j=0;j<4;j++){
      float g;
      spsig_f(acc0[j] + (&ba.x)[j], (&h0.x)[j], g);
      sh_s1L[base0+j][lane_n] = g;
      spsig_f(acc1[j] + (&bb.x)[j], (&h1.x)[j], g);
      sh_s1L[base1+j][lane_n] = g;
    }
    stH4(Bact[0], lane_n, base0, h0);
    stH4(Bact[0], lane_n, base1, h1);
  }
  __syncthreads();

  // load s1 into tangent-staging layout regs (features 2l,2l+1; samples 4w+j)
  float4 s1a, s1b;
  #pragma unroll
  for (int j=0;j<4;j++){
    (&s1a.x)[j] = sh_s1L[2*l  ][4*w+j];
    (&s1b.x)[j] = sh_s1L[2*l+1][4*w+j];
  }

  float4 s2a, s2b;
  // ---- L2L MFMA (mfma2: split weight x fp16 act) + epilogue in-place
  {
    f32x4 acc0 = {0.f,0.f,0.f,0.f}, acc1 = {0.f,0.f,0.f,0.f};
    #pragma unroll
    for (int q=0;q<4;q++){
      half8_t bh = ldB(Bact[0], lane_n, q, quad);
      acc0 = mfma2(fW2Lh[(w*4+q)*64+l],     fW2Ll[(w*4+q)*64+l],     bh, acc0);
      acc1 = mfma2(fW2Lh[((w+4)*4+q)*64+l], fW2Ll[((w+4)*4+q)*64+l], bh, acc1);
    }
    __syncthreads();
    float4 ba = *reinterpret_cast<const float4*>(b2L + base0);
    float4 bb = *reinterpret_cast<const float4*>(b2L + base1);
    float4 h2a, h2b;
    #pragma unroll
    for (int j=0;j<4;j++){
      spsig_f(acc0[j] + (&ba.x)[j], (&h2a.x)[j], (&s2a.x)[j]);
      spsig_f(acc1[j] + (&bb.x)[j], (&h2b.x)[j], (&s2b.x)[j]);
    }
    stH4(Bact[0], lane_n, base0, h2a);
    stH4(Bact[0], lane_n, base1, h2b);
  }
  __syncthreads();

  // ---- L3 MFMA (waves 0,1; mfma2) -> y, s3
  if (w < 2){
    f32x4 acc = {0.f,0.f,0.f,0.f};
    #pragma unroll
    for (int q=0;q<4;q++){
      half8_t bh = ldB(Bact[0], lane_n, q, quad);
      acc = mfma2(fW3h[(w*4+q)*64+l], fW3l[(w*4+q)*64+l], bh, acc);
    }
    int rb = w*16 + quad*4;
    #pragma unroll
    for (int j=0;j<4;j++){
      int r = rb + j;
      if (r < 21){
        float z = acc[j] + b3Lp[r];
        float sp, sg;
        spsig_f(z, sp, sg);
        sh_y[r][lane_n]  = sp;
        sh_s3[r][lane_n] = sg;
      }
    }
  }
  __syncthreads();
  // (Bact dead: sh_y/sh_s3 captured. Bd free for tangents.)

  // ---- v = L^T qdot
  if (tid < 96){
    int s = tid & 15, jj = tid >> 4;
    float acc = 0.f;
    for (int i=jj;i<6;i++) acc = fmaf(sh_y[c_ROWOFF[i]+jj][s], sh_qd[i][s], acc);
    sh_v[jj][s] = acc;
  }

  // ---- tangent groups: dirs {2G, 2G+1} — plain fp16 path
  for (int G=0; G<3; ++G){
    #pragma unroll
    for (int d=0; d<2; ++d){
      int g = 2*G + d;
      float2 w0 = *reinterpret_cast<const float2*>(W1LT + (2*g)*128 + 2*l);
      float2 w1 = *reinterpret_cast<const float2*>(W1LT + (2*g+1)*128 + 2*l);
      float4 tc = *chunkc(sh_t, 2*g,   w);
      float4 ts = *chunkc(sh_t, 2*g+1, w);
      #pragma unroll
      for (int j=0;j<4;j++){
        float tcj = (&tc.x)[j], tsj = (&ts.x)[j];
        float d0 = (&s1a.x)[j]*(tcj*w1.x - tsj*w0.x);
        float d1 = (&s1b.x)[j]*(tcj*w1.y - tsj*w0.y);
        stH2(Bd[d][0], 4*w+j, 2*l, d0, d1);
      }
    }
    __syncthreads();
    f32x4 ta00={0.f,0.f,0.f,0.f}, ta01=ta00, ta10=ta00, ta11=ta00;
    #pragma unroll
    for (int q=0;q<4;q++){
      half8_t b0h = ldB(Bd[0][0], lane_n, q, quad);
      half8_t b1h = ldB(Bd[1][0], lane_n, q, quad);
      half8_t a0h = fW2Lh[(w*4+q)*64+l];
      half8_t a1h = fW2Lh[((w+4)*4+q)*64+l];
      ta00 = mfma1(a0h, b0h, ta00);
      ta01 = mfma1(a0h, b1h, ta01);
      ta10 = mfma1(a1h, b0h, ta10);
      ta11 = mfma1(a1h, b1h, ta11);
    }
    __syncthreads();
    {
      float4 v;
      #pragma unroll
      for (int j=0;j<4;j++) (&v.x)[j] = (&s2a.x)[j]*ta00[j];
      stH4(Bd[0][0], lane_n, base0, v);
      #pragma unroll
      for (int j=0;j<4;j++) (&v.x)[j] = (&s2b.x)[j]*ta10[j];
      stH4(Bd[0][0], lane_n, base1, v);
      #pragma unroll
      for (int j=0;j<4;j++) (&v.x)[j] = (&s2a.x)[j]*ta01[j];
      stH4(Bd[1][0], lane_n, base0, v);
      #pragma unroll
      for (int j=0;j<4;j++) (&v.x)[j] = (&s2b.x)[j]*ta11[j];
      stH4(Bd[1][0], lane_n, base1, v);
    }
    __syncthreads();
    {
      int d = w & 1, tt = w >> 1;
      f32x4 acc = {0.f,0.f,0.f,0.f};
      #pragma unroll
      for (int q=0;q<4;q++){
        half8_t bh = ldB(Bd[d][0], lane_n, q, quad);
        acc = mfma1(fW3h[(tt*4+q)*64+l], bh, acc);
      }
      int rb = tt*16 + quad*4;
      #pragma unroll
      for (int j=0;j<4;j++){
        int r = rb + j;
        if (r < 21) sh_dy[d*21 + r][lane_n] = sh_s3[r][lane_n] * acc[j];
      }
    }
    __syncthreads();   // Bd reads drained; sh_dy ready
    if (tid < 32){
      int s = tid & 15, gg = tid >> 4;
      float qd[6];
      #pragma unroll
      for (int i=0;i<6;i++) qd[i] = sh_qd[i][s];
      float u[6];
      #pragma unroll
      for (int jj=0;jj<6;jj++){
        float acc = 0.f;
        for (int i=jj;i<6;i++) acc = fmaf(sh_dy[gg*21 + c_ROWOFF[i]+jj][s], qd[i], acc);
        u[jj] = acc;
      }
      #pragma unroll
      for (int i=0;i<6;i++){
        float acc = 0.f;
        for (int j=0;j<=i;j++){
          acc = fmaf(sh_dy[gg*21 + c_ROWOFF[i]+j][s], sh_v[j][s], acc);
          acc = fmaf(sh_y [c_ROWOFF[i]+j][s], u[j], acc);
        }
        sh_wg[gg][i][s] = acc;
      }
    }
    __syncthreads();
    if (tid < 96){
      int s = tid & 15, i = tid >> 4;
      float acc = sh_c[i][s];
      acc = fmaf(sh_qd[2*G][s],   sh_wg[0][i][s], acc);
      acc = fmaf(sh_qd[2*G+1][s], sh_wg[1][i][s], acc);
      int gi = i - 2*G;
      if (gi == 0 || gi == 1){
        float r = 0.f;
        #pragma unroll
        for (int j=0;j<6;j++) r = fmaf(sh_qd[j][s], sh_wg[gi][j][s], r);
        acc -= 0.5f*r;
      }
      sh_c[i][s] = acc;
    }
    // NO barrier here (r11 audit): next writes disjoint; Bd readers drained;
    // next sh_wg write is >=2 barriers away.
  }

  // ---- V-net L1 via MFMA (plain fp16); s1V stays in REGISTERS (r13)
  float4 s1Va, s1Vb;
  {
    f32x4 acc0 = {0.f,0.f,0.f,0.f}, acc1 = {0.f,0.f,0.f,0.f};
    acc0 = mfma1(fW1VAh[w*64+l],     tBfrag, acc0);
    acc1 = mfma1(fW1VAh[(w+4)*64+l], tBfrag, acc1);
    float4 ba = *reinterpret_cast<const float4*>(b1V + base0);
    float4 bb = *reinterpret_cast<const float4*>(b1V + base1);
    float4 h0, h1;
    #pragma unroll
    for (int j=0;j<4;j++){
      spsig_f(acc0[j] + (&ba.x)[j], (&h0.x)[j], (&s1Va.x)[j]);
      spsig_f(acc1[j] + (&bb.x)[j], (&h1.x)[j], (&s1Vb.x)[j]);
    }
    stH4(Bact[0], lane_n, base0, h0);
    stH4(Bact[0], lane_n, base1, h1);
  }
  __syncthreads();
  // ---- L2V MFMA (plain fp16); epilogue g2 = sig(z)*W3V -> Bact in-place
  {
    f32x4 acc0 = {0.f,0.f,0.f,0.f}, acc1 = {0.f,0.f,0.f,0.f};
    #pragma unroll
    for (int q=0;q<4;q++){
      half8_t bh = ldB(Bact[0], lane_n, q, quad);
      acc0 = mfma1(fW2Vh[(w*4+q)*64+l],     bh, acc0);
      acc1 = mfma1(fW2Vh[((w+4)*4+q)*64+l], bh, acc1);
    }
    __syncthreads();
    float4 ba  = *reinterpret_cast<const float4*>(b2V + base0);
    float4 bb  = *reinterpret_cast<const float4*>(b2V + base1);
    float4 w3a = *reinterpret_cast<const float4*>(W3V + base0);
    float4 w3b = *reinterpret_cast<const float4*>(W3V + base1);
    float4 g2a, g2b;
    #pragma unroll
    for (int j=0;j<4;j++){
      (&g2a.x)[j] = sig_f(acc0[j] + (&ba.x)[j]) * (&w3a.x)[j];
      (&g2b.x)[j] = sig_f(acc1[j] + (&bb.x)[j]) * (&w3b.x)[j];
    }
    stH4(Bact[0], lane_n, base0, g2a);
    stH4(Bact[0], lane_n, base1, g2b);
  }
  __syncthreads();
  // ---- V bwd MFMA (A = W2V^T, plain fp16); epilogue: g1 = s1V(regs) * acc
  // ALIAS HAZARD: reads Bact[0] (g2), writes g1 to same buffer; barrier
  // below orders all reads before any write.
  {
    f32x4 acc0 = {0.f,0.f,0.f,0.f}, acc1 = {0.f,0.f,0.f,0.f};
    #pragma unroll
    for (int q=0;q<4;q++){
      half8_t bh = ldB(Bact[0], lane_n, q, quad);
      acc0 = mfma1(fW2VTh[(w*4+q)*64+l],     bh, acc0);
      acc1 = mfma1(fW2VTh[((w+4)*4+q)*64+l], bh, acc1);
    }
    float4 g1a, g1b;
    #pragma unroll
    for (int j=0;j<4;j++){
      (&g1a.x)[j] = (&s1Va.x)[j] * acc0[j];
      (&g1b.x)[j] = (&s1Vb.x)[j] * acc1[j];
    }
    __syncthreads();   // all g2 reads complete before g1 overwrite (alias)
    stH4(Bact[0], lane_n, base0, g1a);
    stH4(Bact[0], lane_n, base1, g1b);
  }
  __syncthreads();
  // ---- dV/dt = W1V^T g1 via MFMA (wave 0 only; plain fp16)
  if (w == 0){
    f32x4 acc = {0.f,0.f,0.f,0.f};
    #pragma unroll
    for (int q=0;q<4;q++){
      half8_t bh = ldB(Bact[0], lane_n, q, quad);
      acc = mfma1(fW1Th[q*64+l], bh, acc);
    }
    int rb = quad*4;
    #pragma unroll
    for (int j=0;j<4;j++){
      int r = rb + j;
      if (r < 12) sh_dv[r][lane_n] = acc[j];
    }
  }
  __syncthreads();
  // ---- assembly + triangular solves + folded next-stage pre (+ final)
  // gravity inline (r11).
  if (l < 4){
    int s = w*4 + l;
    float Lm[21];
    #pragma unroll
    for (int o=0;o<21;o++) Lm[o] = sh_y[o][s];
    float rhs[6];
    #pragma unroll
    for (int i=0;i<6;i++){
      float grav = fmaf(el(sh_t,2*i,s), sh_dv[2*i+1][s],
                        -(el(sh_t,2*i+1,s)*sh_dv[2*i][s]));
      rhs[i] = sh_tau[i][s] - sh_c[i][s] - grav - sh_f[i][s];
    }
    float z[6];
    #pragma unroll
    for (int i=0;i<6;i++){
      float acc = rhs[i];
      for (int j=0;j<i;j++) acc = fmaf(-Lm[c_ROWOFF[i]+j], z[j], acc);
      z[i] = acc * __builtin_amdgcn_rcpf(Lm[c_ROWOFF[i]+i]);
    }
    float a[6];
    #pragma unroll
    for (int i=5;i>=0;i--){
      float acc = z[i];
      for (int j=i+1;j<6;j++) acc = fmaf(-Lm[c_ROWOFF[j]+i], a[j], acc);
      a[i] = acc * __builtin_amdgcn_rcpf(Lm[c_ROWOFF[i]+i]);
    }
    int b = s0 + s;
    float* kqd_out = kqd_all + stage*B6;
    #pragma unroll
    for (int i=0;i<6;i++) kqd_out[b*6+i] = a[i];

    if (stage < 3){
      const float* o = obs + b*12;
      unsigned mask = 0;
      #pragma unroll
      for (int i=0;i<6;i++){
        float q0=o[i], qd0=o[6+i];
        float q, qd;
        if (stage == 0){
          q  = q0 + 0.5f*DT*qd0;
          qd = qd0 + 0.5f*DT*a[i];
        } else if (stage == 1){
          float k1 = kqd_all[b*6+i];
          q  = q0 + 0.5f*DT*qd0 + 0.25f*DT*DT*k1;
          qd = qd0 + 0.5f*DT*a[i];
        } else {
          float k2 = kqd_all[B6 + b*6+i];
          q  = q0 + DT*qd0 + 0.5f*DT*DT*k2;
          qd = qd0 + DT*a[i];
        }
        q_cur[b*6+i]=q; qd_cur[b*6+i]=qd;
        float lo = c_LOWER[i]+0.1f, up = c_UPPER[i]-0.1f;
        if (q <= lo || q >= up) mask |= (1u<<i);
      }
      if (mask) atomicOr(viol + stage + 1, (int)mask);
    }

    if (fold_final){
      const float* o = obs + b*12;
      float* po = out + b*12;
      #pragma unroll
      for (int i=0;i<6;i++){
        float q0=o[i], qd0=o[6+i];
        float k1=kqd_all[b*6+i], k2=kqd_all[B6+b*6+i], k3=kqd_all[2*B6+b*6+i];
        float qn = q0 + DT*qd0 + (DT*DT/6.0f)*(k1+k2+k3);
        qn = fminf(fmaxf(qn, c_LOWER[i]), c_UPPER[i]);
        po[i] = qn;
        po[6+i] = qd0 + (DT/6.0f)*(k1 + 2.0f*k2 + 2.0f*k3 + a[i]);
      }
    }
  }
  #undef Bact
}

extern "C" void kernel_launch(void* const* d_in, const int* in_sizes, int n_in,
                              void* d_out, int out_size, void* d_ws, size_t ws_size,
                              hipStream_t stream) {
  const float* obs    = (const float*)d_in[0];
  const float* action = (const float*)d_in[1];
  const float* W1L = (const float*)d_in[2];  const float* b1L = (const float*)d_in[3];
  const float* W2L = (const float*)d_in[4];  const float* b2L = (const float*)d_in[5];
  const float* W3L = (const float*)d_in[6];  const float* b3L = (const float*)d_in[7];
  const float* W1V = (const float*)d_in[8];  const float* b1V = (const float*)d_in[9];
  const float* W2V = (const float*)d_in[10]; const float* b2V = (const float*)d_in[11];
  const float* W3V = (const float*)d_in[12]; // b3V unused: only grad of V needed

  float* ws = (float*)d_ws;
  _Float16* fragHi = (_Float16*)ws;            // 65536 halves (r13: +L1 A-frags)
  _Float16* fragLo = fragHi + 65536;           // 65536 halves
  float* W1LT  = ws + 65536;                   // 1536 (131072 halves = 65536 floats)
  float* W1VT  = W1LT + 1536;                  // 1536
  float* b3Lp  = W1VT + 1536;                  // 32
  float* q_cur  = b3Lp + 32;                   // B6
  float* qd_cur = q_cur + B6;                  // B6
  float* kqd    = qd_cur + B6;                 // 4*B6
  int*   viol   = (int*)(kqd + 4*B6);

  float* out = (float*)d_out;

  hipMemsetAsync(viol, 0, sizeof(int), stream);
  k_initpre<<<64,256,0,stream>>>(W1L, W2L, W3L, W1V, W2V, b3L, obs,
                                 W1LT, W1VT, b3Lp, fragHi, fragLo,
                                 q_cur, qd_cur, viol);
  for (int s=0; s<4; ++s){
    k_accel<<<1024,256,0,stream>>>(s, (s==3)?1:0, obs, q_cur, qd_cur, action,
        W1LT, b1L, b2L, b3Lp, W1VT, b1V, b2V, W3V, W1V,
        fragHi, fragLo, viol, kqd, out);
  }
}